// Round 10
// baseline (460.621 us; speedup 1.0000x reference)
//
#include <hip/hip_runtime.h>
#include <hip/hip_bf16.h>

typedef __hip_bfloat16 bf16;
typedef __attribute__((ext_vector_type(8))) short bf16x8v;
typedef __attribute__((ext_vector_type(4))) short bf16x4v;
typedef __attribute__((ext_vector_type(4))) float f32x4v;

#define B_ 8
#define C_ 256
#define L_ 128
#define MB 1048576UL

__device__ inline float b2f(bf16 v){ return __bfloat162float(v); }
__device__ inline bf16 f2b(float v){ return __float2bfloat16(v); }
__device__ inline short b2s(bf16 v){ return *(short*)&v; }
__device__ inline float siluf(float x){ return x / (1.f + expf(-x)); }
__device__ inline float softplusf(float x){ return (x > 20.f) ? x : log1pf(expf(x)); }
__device__ inline float vclamp(float v){ return fmaxf(v, 0.f) + 1e-5f; }

// block = 256 threads (4 waves). red must hold >=16 floats.
__device__ inline void bred2(float& a, float& b, float* red){
  #pragma unroll
  for (int m = 1; m < 64; m <<= 1){ a += __shfl_xor(a, m); b += __shfl_xor(b, m); }
  int tid = threadIdx.x, wave = tid >> 6, lane = tid & 63;
  __syncthreads();                       // protect red[] reuse across calls
  if (lane == 0){ red[wave] = a; red[8 + wave] = b; }
  __syncthreads();
  a = red[0] + red[1] + red[2] + red[3];
  b = red[8] + red[9] + red[10] + red[11];
}

// LDS transpose-tile swizzle: 64p x 256c bf16 (32KB linear).
// s(p) = ((p ^ (p>>2)) & 7) << 4 injects BOTH p bits 0-2 (read lanes: l16)
// and p bits 2-4 (write lanes: pc) into byte bits 4-6. 2 lanes/bank both ways (free).
__device__ inline int tswz(int p, int c){
  return (p*512 + c*2) ^ (((p ^ (p >> 2)) & 7) << 4);
}

// ---------------- pooling step 1: row/col max/min + argmax + pos-embed -------------
// float4 global loads (G13); scalar LDS writes keep the [65]-pad conflict-free reads.
// grid (C, B), block 64
__global__ __launch_bounds__(64) void pool1_kernel(const float* __restrict__ x, const float* __restrict__ pos,
    float* __restrict__ pcolmax, float* __restrict__ pcolmin,
    float* __restrict__ prowmax, float* __restrict__ prowmin, float* __restrict__ sxb)
{
  int c = blockIdx.x, b = blockIdx.y, t = threadIdx.x;
  __shared__ float xs[64][65];
  const float* xp = x + ((long)(b*C_ + c))*4096;
  const float4* xp4 = (const float4*)xp;
  #pragma unroll
  for (int q = 0; q < 16; q++){
    float4 v = xp4[q*64 + t];
    int e = q*64 + t;
    int i = e >> 4, cc = (e & 15) << 2;
    xs[i][cc] = v.x; xs[i][cc+1] = v.y; xs[i][cc+2] = v.z; xs[i][cc+3] = v.w;
  }
  __syncthreads();
  // jax.image.resize 'linear' 16->64: half-pixel coords, edge clamp
  float tt = 0.25f*(float)t - 0.375f;
  const float* pp = pos + c*16;
  float pe;
  if (tt <= 0.f) pe = pp[0];
  else if (tt >= 15.f) pe = pp[15];
  else { int f = (int)floorf(tt); float w = tt - (float)f; pe = pp[f]*(1.f - w) + pp[f+1]*w; }
  float vmax = -1e30f, vmin = 1e30f; int amax = 0, amin = 0;
  for (int j = 0; j < 64; j++){
    float v = xs[t][j];
    if (v > vmax){ vmax = v; amax = j; }
    if (v < vmin){ vmin = v; amin = j; }
  }
  long o = (long)(b*64 + t)*C_ + c;
  prowmax[o] = vmax + pe + (float)amax;
  prowmin[o] = vmin + pe + (float)amin;
  vmax = -1e30f; vmin = 1e30f; amax = 0; amin = 0;
  float sx = 0.f, sx2 = 0.f;
  for (int i = 0; i < 64; i++){
    float v = xs[i][t];
    if (v > vmax){ vmax = v; amax = i; }
    if (v < vmin){ vmin = v; amin = i; }
    sx += v; sx2 += v*v;
  }
  pcolmax[o] = vmax + pe + (float)amax;
  pcolmin[o] = vmin + pe + (float)amin;
  #pragma unroll
  for (int m = 1; m < 64; m <<= 1){ sx += __shfl_xor(sx, m); sx2 += __shfl_xor(sx2, m); }
  if (t == 0){ sxb[(b << 8) + c] = sx; sxb[2048 + (b << 8) + c] = sx2; }
}

// ---------------- pooling step 2: LN over channels, write 4 mamba inputs (bf16) ----
// grid (128, B), block 256
__global__ __launch_bounds__(256) void pool2_kernel(const float* __restrict__ pcolmax, const float* __restrict__ pcolmin,
    const float* __restrict__ prowmax, const float* __restrict__ prowmin,
    const float* __restrict__ lnw, const float* __restrict__ lnb, bf16* __restrict__ hbuf)
{
  int r = blockIdx.x, b = blockIdx.y, c = threadIdx.x;
  __shared__ float red[16];
  int p = r & 63;
  long src = (long)(b*64 + p)*C_ + c;
  float vmax = (r < 64) ? pcolmax[src] : prowmax[src];
  float vmin = (r < 64) ? pcolmin[src] : prowmin[src];
  float gw = lnw[c], gb = lnb[c];
  long row = (long)b*L_ + r, frow = (long)b*L_ + (127 - r);
  float s = vmax, s2 = vmax*vmax;
  bred2(s, s2, red);
  float m = s*(1.f/256.f), var = s2*(1.f/256.f) - m*m;
  float o = (vmax - m)*rsqrtf(vclamp(var))*gw + gb;
  hbuf[0*262144 + row*C_ + c]  = f2b(o);
  hbuf[2*262144 + frow*C_ + c] = f2b(o);
  s = vmin; s2 = vmin*vmin;
  bred2(s, s2, red);
  m = s*(1.f/256.f); var = s2*(1.f/256.f) - m*m;
  o = (vmin - m)*rsqrtf(vclamp(var))*gw + gb;
  hbuf[1*262144 + row*C_ + c]  = f2b(o);
  hbuf[3*262144 + frow*C_ + c] = f2b(o);
}

// ---------------- z1raw = dwconvT(x) as bf16 + bn1 stats (one pass) ----------------
// 2x2 output-quad specialization (bit-exact). grid (B*C), block 256.
__global__ __launch_bounds__(256) void dwz1_kernel(const float* __restrict__ x, const float* __restrict__ dw,
    bf16* __restrict__ z1, float* __restrict__ bn1sum, float* __restrict__ bn1sq)
{
  int bc = blockIdx.x; int c = bc & 255;
  int tid = threadIdx.x;
  __shared__ __align__(16) float xs[4096];
  const float4* xp4 = (const float4*)(x + (long)bc*4096);
  #pragma unroll
  for (int q = 0; q < 4; q++)
    *(float4*)&xs[(q*256 + tid)*4] = xp4[q*256 + tid];
  float w[9];
  #pragma unroll
  for (int q = 0; q < 9; q++) w[q] = dw[c*9 + q];
  __syncthreads();
  bf16* zp = z1 + (long)bc*16384;
  float s = 0.f, s2 = 0.f;
  for (int it = 0; it < 16; it++){
    int q = it*256 + tid;            // quad id 0..4095
    int a = q >> 6, bq = q & 63;
    int a1 = (a < 63) ? a + 1 : 63;
    int b1 = (bq < 63) ? bq + 1 : 63;
    float XA = xs[a*64 + bq];
    float XB = xs[a*64 + b1];
    float XC = xs[a1*64 + bq];
    float XD = xs[a1*64 + b1];
    float w3e = (bq < 63) ? w[3] : 0.f;
    float w6e = (bq < 63) ? w[6] : 0.f;
    float w1e = (a < 63) ? w[1] : 0.f;
    float w2e = (a < 63) ? w[2] : 0.f;
    float w0e = (a < 63 && bq < 63) ? w[0] : 0.f;
    float o00 = w[4]*XA; o00 += 0.f*XB; o00 += 0.f*XC; o00 += 0.f*XD;
    float o01 = w[5]*XA; o01 += w3e*XB; o01 += 0.f*XC; o01 += 0.f*XD;
    float o10 = w[7]*XA; o10 += 0.f*XB; o10 += w1e*XC; o10 += 0.f*XD;
    float o11 = w[8]*XA; o11 += w6e*XB; o11 += w2e*XC; o11 += w0e*XD;
    bf16 r0[2] = {f2b(o00), f2b(o01)};
    bf16 r1[2] = {f2b(o10), f2b(o11)};
    *(unsigned int*)&zp[(2*a)*128 + 2*bq]     = *(const unsigned int*)r0;
    *(unsigned int*)&zp[(2*a + 1)*128 + 2*bq] = *(const unsigned int*)r1;
    s += o00; s2 += o00*o00;
    s += o01; s2 += o01*o01;
    s += o10; s2 += o10*o10;
    s += o11; s2 += o11*o11;
  }
  __shared__ float red[16];
  bred2(s, s2, red);
  if (tid == 0){ atomicAdd(&bn1sum[c], s); atomicAdd(&bn1sq[c], s2); }
}

// ---------------- all fp32 -> bf16 weight converts in ONE launch -------------------
// grid (256, 9), block 256; 4 elems/thread.
__global__ __launch_bounds__(256) void wcvt_all_kernel(
    const float* __restrict__ s0, const float* __restrict__ s1, const float* __restrict__ s2,
    const float* __restrict__ s3, const float* __restrict__ s4, const float* __restrict__ s5,
    const float* __restrict__ s6, const float* __restrict__ s7, const float* __restrict__ s8,
    bf16* __restrict__ d0, bf16* __restrict__ d1, bf16* __restrict__ d2,
    bf16* __restrict__ d3, bf16* __restrict__ d4, bf16* __restrict__ d5,
    bf16* __restrict__ d6, bf16* __restrict__ d7, bf16* __restrict__ d8)
{
  int seg = blockIdx.y;
  const float* s; bf16* d; int n;
  switch (seg){
    case 0: s = s0; d = d0; n = 262144; break;
    case 1: s = s1; d = d1; n = 262144; break;
    case 2: s = s2; d = d2; n = 24576;  break;
    case 3: s = s3; d = d3; n = 24576;  break;
    case 4: s = s4; d = d4; n = 131072; break;
    case 5: s = s5; d = d5; n = 131072; break;
    case 6: s = s6; d = d6; n = 131072; break;
    case 7: s = s7; d = d7; n = 65536;  break;
    default: s = s8; d = d8; n = 65536; break;
  }
  long i = ((long)blockIdx.x*256 + threadIdx.x)*4;
  if (i >= n) return;
  float4 v = *(const float4*)&s[i];
  bf16 o[4] = {f2b(v.x), f2b(v.y), f2b(v.z), f2b(v.w)};
  *(uint2*)&d[i] = *(const uint2*)o;
}

// ---------------- FUSED up-pw (swapped-MFMA epilogue, aa/dd LDS table) -------------
// grid (256, B), block 256.
__global__ __launch_bounds__(256) void pwz_fused_kernel(const bf16* __restrict__ z1,
    const float* __restrict__ bn1sum, const float* __restrict__ bn1sq,
    const float* __restrict__ g1, const float* __restrict__ b1,
    const bf16* __restrict__ Wb, bf16* __restrict__ z2,
    float* __restrict__ bn2part)
{
  int b = blockIdx.y;
  int p0 = blockIdx.x*64;
  int tid = threadIdx.x;
  __shared__ __align__(16) short Tb[16384];   // 64p x 256c bf16, tswz layout
  __shared__ float aa[256], dd[256];
  {
    float m = bn1sum[tid]*(1.f/131072.f);
    float v = bn1sq[tid]*(1.f/131072.f) - m*m;
    float a = g1[tid]*rsqrtf(vclamp(v));
    aa[tid] = a; dd[tid] = b1[tid] - m*a;
  }
  __syncthreads();
  {
    int pc = tid & 15, ch = tid >> 4;
    #pragma unroll
    for (int it = 0; it < 8; it++){
      int c = (ch + it*16)*2;
      const bf16* r0 = &z1[((long)(b*C_ + c))*16384 + p0 + pc*4];
      bf16x4v va = *(const bf16x4v*)r0;
      bf16x4v vb = *(const bf16x4v*)(r0 + 16384);
      float a0 = aa[c], d0 = dd[c], a1 = aa[c+1], d1 = dd[c+1];
      #pragma unroll
      for (int k = 0; k < 4; k++){
        int p = pc*4 + k;
        bf16 h0; *(short*)&h0 = va[k];
        bf16 h1; *(short*)&h1 = vb[k];
        bf16 o0 = f2b(fmaxf(b2f(h0)*a0 + d0, 0.f));
        bf16 o1 = f2b(fmaxf(b2f(h1)*a1 + d1, 0.f));
        unsigned int u = ((unsigned int)(*(unsigned short*)&o1) << 16) | (unsigned int)(*(unsigned short*)&o0);
        *(unsigned int*)((char*)Tb + tswz(p, c)) = u;
      }
    }
  }
  __syncthreads();
  int wave = tid >> 6, lane = tid & 63;
  int quad = lane >> 4, l16 = lane & 15;
  f32x4v acc[4][4];
  #pragma unroll
  for (int i = 0; i < 4; i++)
    #pragma unroll
    for (int j = 0; j < 4; j++) acc[i][j] = (f32x4v){0.f, 0.f, 0.f, 0.f};
  for (int k0 = 0; k0 < 256; k0 += 32){
    int c = k0 + quad*8;
    bf16x8v a[4], bb[4];
    #pragma unroll
    for (int ms = 0; ms < 4; ms++)
      a[ms] = *(const bf16x8v*)&Wb[(wave*64 + ms*16 + l16)*C_ + c];
    #pragma unroll
    for (int ns = 0; ns < 4; ns++){
      int p = ns*16 + l16;
      bb[ns] = *(const bf16x8v*)((const char*)Tb + tswz(p, c));
    }
    // swapped operands: acc[ms][ns] holds rows p = ns*16+quad*4+r, col o-sub = l16
    #pragma unroll
    for (int ms = 0; ms < 4; ms++)
      #pragma unroll
      for (int ns = 0; ns < 4; ns++)
        acc[ms][ns] = __builtin_amdgcn_mfma_f32_16x16x32_bf16(bb[ns], a[ms], acc[ms][ns], 0, 0, 0);
  }
  int slot = (blockIdx.x & 7) | (b << 3);
  #pragma unroll
  for (int ms = 0; ms < 4; ms++){
    int o = wave*64 + ms*16 + l16;          // this lane's output channel
    long rowbase = ((long)(b*C_ + o))*16384 + p0;
    float s = 0.f, s2 = 0.f;
    #pragma unroll
    for (int ns = 0; ns < 4; ns++){
      bf16 ov[4];
      #pragma unroll
      for (int r = 0; r < 4; r++){
        bf16 bv = f2b(acc[ms][ns][r]);
        ov[r] = bv;
        float vv = b2f(bv);
        s += vv; s2 += vv*vv;
      }
      *(uint2*)&z2[rowbase + ns*16 + quad*4] = *(const uint2*)ov;
    }
    s += __shfl_xor(s, 16);  s += __shfl_xor(s, 32);
    s2 += __shfl_xor(s2, 16); s2 += __shfl_xor(s2, 32);
    if (quad == 0){
      atomicAdd(&bn2part[slot*256 + o], s);
      atomicAdd(&bn2part[16384 + slot*256 + o], s2);
    }
  }
}

// ---------------- in_proj GEMM on MFMA (swapped epilogue): xz = hb @ Wi^T ----------
// M=1024, N=1024, K=256, bf16 out. grid (16, 4, 4), block 256.
__global__ __launch_bounds__(256) void inproj_mfma_kernel(const bf16* __restrict__ hb,
    const bf16* __restrict__ Wif, const bf16* __restrict__ Wib2, bf16* __restrict__ xz)
{
  int v = blockIdx.z;
  int m0 = blockIdx.y*256, n0 = blockIdx.x*64;
  const bf16* A = hb + (long)v*262144;
  const bf16* W = (v >= 2) ? Wib2 : Wif;
  bf16* out = xz + (long)v*1048576;
  int tid = threadIdx.x;
  int wave = tid >> 6, lane = tid & 63;
  int quad = lane >> 4, l16 = lane & 15;
  f32x4v acc[4][4];
  #pragma unroll
  for (int i = 0; i < 4; i++)
    #pragma unroll
    for (int j = 0; j < 4; j++) acc[i][j] = (f32x4v){0.f, 0.f, 0.f, 0.f};
  for (int k0 = 0; k0 < 256; k0 += 32){
    int c = k0 + quad*8;
    bf16x8v a[4], bb[4];
    #pragma unroll
    for (int ms = 0; ms < 4; ms++)
      a[ms] = *(const bf16x8v*)&A[(long)(m0 + wave*64 + ms*16 + l16)*256 + c];
    #pragma unroll
    for (int ns = 0; ns < 4; ns++)
      bb[ns] = *(const bf16x8v*)&W[(long)(n0 + ns*16 + l16)*256 + c];
    #pragma unroll
    for (int ms = 0; ms < 4; ms++)
      #pragma unroll
      for (int ns = 0; ns < 4; ns++)
        acc[ms][ns] = __builtin_amdgcn_mfma_f32_16x16x32_bf16(bb[ns], a[ms], acc[ms][ns], 0, 0, 0);
  }
  #pragma unroll
  for (int ms = 0; ms < 4; ms++){
    int m = m0 + wave*64 + ms*16 + l16;
    #pragma unroll
    for (int ns = 0; ns < 4; ns++){
      bf16 ov[4];
      #pragma unroll
      for (int r = 0; r < 4; r++) ov[r] = f2b(acc[ms][ns][r]);
      *(uint2*)&out[(long)m*1024 + n0 + ns*16 + quad*4] = *(const uint2*)ov;
    }
  }
}

// ---------------- x_proj GEMM on MFMA (swapped epilogue) ---------------------------
// M=1024, N=48, K=512. grid (4 mtile, 4 v), block 256.
__global__ __launch_bounds__(256) void xproj_mfma_kernel(const bf16* __restrict__ ub,
    const bf16* __restrict__ Wxf, const bf16* __restrict__ Wxb, float* __restrict__ dblb)
{
  int v = blockIdx.y;
  int m0 = blockIdx.x*256;
  const bf16* A = ub + (long)v*524288;
  const bf16* W = (v >= 2) ? Wxb : Wxf;
  float* out = dblb + (long)v*49152;
  int tid = threadIdx.x;
  int wave = tid >> 6, lane = tid & 63;
  int quad = lane >> 4, l16 = lane & 15;
  f32x4v acc[4][3];
  #pragma unroll
  for (int i = 0; i < 4; i++)
    #pragma unroll
    for (int j = 0; j < 3; j++) acc[i][j] = (f32x4v){0.f, 0.f, 0.f, 0.f};
  for (int k0 = 0; k0 < 512; k0 += 32){
    int c = k0 + quad*8;
    bf16x8v a[4], bb[3];
    #pragma unroll
    for (int ms = 0; ms < 4; ms++)
      a[ms] = *(const bf16x8v*)&A[(long)(m0 + wave*64 + ms*16 + l16)*512 + c];
    #pragma unroll
    for (int ns = 0; ns < 3; ns++)
      bb[ns] = *(const bf16x8v*)&W[(long)(ns*16 + l16)*512 + c];
    #pragma unroll
    for (int ms = 0; ms < 4; ms++)
      #pragma unroll
      for (int ns = 0; ns < 3; ns++)
        acc[ms][ns] = __builtin_amdgcn_mfma_f32_16x16x32_bf16(bb[ns], a[ms], acc[ms][ns], 0, 0, 0);
  }
  #pragma unroll
  for (int ms = 0; ms < 4; ms++){
    int m = m0 + wave*64 + ms*16 + l16;
    #pragma unroll
    for (int ns = 0; ns < 3; ns++)
      *(f32x4v*)&out[(long)m*48 + ns*16 + quad*4] = acc[ms][ns];
  }
}

// ---------------- out_proj GEMM on MFMA (swapped epilogue) -------------------------
// M=1024, N=256, K=512. grid (4 ntile, 4 mtile, 4 v), block 256.
__global__ __launch_bounds__(256) void outproj_mfma_kernel(const bf16* __restrict__ yb,
    const bf16* __restrict__ Wof, const bf16* __restrict__ Wob, float* __restrict__ mo)
{
  int v = blockIdx.z;
  int m0 = blockIdx.y*256, n0 = blockIdx.x*64;
  const bf16* A = yb + (long)v*524288;
  const bf16* W = (v >= 2) ? Wob : Wof;
  float* out = mo + (long)v*262144;
  int tid = threadIdx.x;
  int wave = tid >> 6, lane = tid & 63;
  int quad = lane >> 4, l16 = lane & 15;
  f32x4v acc[4][4];
  #pragma unroll
  for (int i = 0; i < 4; i++)
    #pragma unroll
    for (int j = 0; j < 4; j++) acc[i][j] = (f32x4v){0.f, 0.f, 0.f, 0.f};
  for (int k0 = 0; k0 < 512; k0 += 32){
    int c = k0 + quad*8;
    bf16x8v a[4], bb[4];
    #pragma unroll
    for (int ms = 0; ms < 4; ms++)
      a[ms] = *(const bf16x8v*)&A[(long)(m0 + wave*64 + ms*16 + l16)*512 + c];
    #pragma unroll
    for (int ns = 0; ns < 4; ns++)
      bb[ns] = *(const bf16x8v*)&W[(long)(n0 + ns*16 + l16)*512 + c];
    #pragma unroll
    for (int ms = 0; ms < 4; ms++)
      #pragma unroll
      for (int ns = 0; ns < 4; ns++)
        acc[ms][ns] = __builtin_amdgcn_mfma_f32_16x16x32_bf16(bb[ns], a[ms], acc[ms][ns], 0, 0, 0);
  }
  #pragma unroll
  for (int ms = 0; ms < 4; ms++){
    int m = m0 + wave*64 + ms*16 + l16;
    #pragma unroll
    for (int ns = 0; ns < 4; ns++)
      *(f32x4v*)&out[(long)m*256 + n0 + ns*16 + quad*4] = acc[ms][ns];
  }
}

// ---------------- proj GEMM on MFMA (swapped epilogue, +bias) ----------------------
// M=1024, N=256, K=512, z=2. grid (4 ntile, 4 mtile, 2), block 256.
__global__ __launch_bounds__(256) void pj_mfma_kernel(const bf16* __restrict__ cb,
    const bf16* __restrict__ Wp, const float* __restrict__ pb, float* __restrict__ rp)
{
  int z = blockIdx.z;
  int m0 = blockIdx.y*256, n0 = blockIdx.x*64;
  const bf16* A = cb + (long)z*524288;
  float* out = rp + (long)z*262144;
  int tid = threadIdx.x;
  int wave = tid >> 6, lane = tid & 63;
  int quad = lane >> 4, l16 = lane & 15;
  f32x4v acc[4][4];
  #pragma unroll
  for (int i = 0; i < 4; i++)
    #pragma unroll
    for (int j = 0; j < 4; j++) acc[i][j] = (f32x4v){0.f, 0.f, 0.f, 0.f};
  for (int k0 = 0; k0 < 512; k0 += 32){
    int c = k0 + quad*8;
    bf16x8v a[4], bb[4];
    #pragma unroll
    for (int ms = 0; ms < 4; ms++)
      a[ms] = *(const bf16x8v*)&A[(long)(m0 + wave*64 + ms*16 + l16)*512 + c];
    #pragma unroll
    for (int ns = 0; ns < 4; ns++)
      bb[ns] = *(const bf16x8v*)&Wp[(long)(n0 + ns*16 + l16)*512 + c];
    #pragma unroll
    for (int ms = 0; ms < 4; ms++)
      #pragma unroll
      for (int ns = 0; ns < 4; ns++)
        acc[ms][ns] = __builtin_amdgcn_mfma_f32_16x16x32_bf16(bb[ns], a[ms], acc[ms][ns], 0, 0, 0);
  }
  #pragma unroll
  for (int ns = 0; ns < 4; ns++){
    float4 pbv = *(const float4*)&pb[n0 + ns*16 + quad*4];
    #pragma unroll
    for (int ms = 0; ms < 4; ms++){
      int m = m0 + wave*64 + ms*16 + l16;
      f32x4v vv = acc[ms][ns];
      vv[0] += pbv.x; vv[1] += pbv.y; vv[2] += pbv.z; vv[3] += pbv.w;
      *(f32x4v*)&out[(long)m*256 + n0 + ns*16 + quad*4] = vv;
    }
  }
}

// ---------------- generic GEMM (dt-proj only; act==3 -> softplus + bf16 store) -----
// grid ((N+63)/64, (M+63)/64, nbatch), block 256
__global__ __launch_bounds__(256) void gemm_kernel(
  const float* __restrict__ Abase, long sA, int lda,
  const float* __restrict__ W0, const float* __restrict__ W1,
  const float* __restrict__ bias0, const float* __restrict__ bias1, int wsplit,
  float* __restrict__ Cbase, long sC, int ldc,
  int M, int N, int K, int act)
{
  int z = blockIdx.z;
  const float* A = Abase + (long)z*sA;
  const float* W = (z >= wsplit) ? W1 : W0;
  const float* bias = (z >= wsplit) ? bias1 : bias0;
  int m0 = blockIdx.y*64, n0 = blockIdx.x*64;
  __shared__ __align__(16) float As[16][68];
  __shared__ __align__(16) float Ws[16][68];
  int tid = threadIdx.x, tx = tid & 15, ty = tid >> 4;
  float acc[4][4] = {};
  for (int k0 = 0; k0 < K; k0 += 16){
    #pragma unroll
    for (int q = 0; q < 4; q++){
      int e = tid + q*256; int r = e >> 4, kk = e & 15;
      int mi = m0 + r, ki = k0 + kk;
      As[kk][r] = (mi < M && ki < K) ? A[(long)mi*lda + ki] : 0.f;
    }
    #pragma unroll
    for (int q = 0; q < 4; q++){
      int e = tid + q*256; int n = e >> 4, kk = e & 15;
      int ni = n0 + n, ki = k0 + kk;
      Ws[kk][n] = (ni < N && ki < K) ? W[(long)ni*K + ki] : 0.f;
    }
    __syncthreads();
    #pragma unroll
    for (int kk = 0; kk < 16; kk++){
      float4 a4 = *(const float4*)&As[kk][ty*4];
      float4 b4 = *(const float4*)&Ws[kk][tx*4];
      float av[4] = {a4.x, a4.y, a4.z, a4.w};
      float bv[4] = {b4.x, b4.y, b4.z, b4.w};
      #pragma unroll
      for (int mm = 0; mm < 4; mm++)
        #pragma unroll
        for (int nn = 0; nn < 4; nn++) acc[mm][nn] += av[mm]*bv[nn];
    }
    __syncthreads();
  }
  #pragma unroll
  for (int mm = 0; mm < 4; mm++){
    int mi = m0 + ty*4 + mm;
    if (mi >= M) continue;
    #pragma unroll
    for (int nn = 0; nn < 4; nn++){
      int ni = n0 + tx*4 + nn;
      if (ni >= N) continue;
      float v = acc[mm][nn];
      if (bias) v += bias[ni];
      if (act >= 2) v = softplusf(v);
      if (act == 3){
        bf16* Cb = (bf16*)Cbase + (long)z*sC;
        Cb[(long)mi*ldc + ni] = f2b(v);
      } else {
        float* Cp = Cbase + (long)z*sC;
        Cp[(long)mi*ldc + ni] = v;
      }
    }
  }
}

// ---------------- depthwise causal conv1d (k=4) + silu, bf16 in/out ----------------
// grid (L, B, 4), block 512
__global__ __launch_bounds__(512) void conv1d_kernel(const bf16* __restrict__ xzb,
    const float* __restrict__ fw, const float* __restrict__ fb,
    const float* __restrict__ bw, const float* __restrict__ bb,
    bf16* __restrict__ ub)
{
  int l = blockIdx.x, b = blockIdx.y, v = blockIdx.z, d = threadIdx.x;
  const bf16* xm = xzb + (long)v*1024*1024;
  const float* w  = (v < 2) ? fw : bw;
  const float* cb = (v < 2) ? fb : bb;
  float acc = cb[d];
  #pragma unroll
  for (int k = 0; k < 4; k++){
    int ll = l - 3 + k;
    if (ll >= 0) acc += b2f(xm[(long)(b*L_ + ll)*1024 + d]) * w[d*4 + k];
  }
  ub[(long)v*1024*512 + (long)(b*L_ + l)*512 + d] = f2b(siluf(acc));
}

// ---------------- selective scan (8-way state split, XCD-local swizzle, vec stage) -
// flat grid 2048. fid = g + k*256, g = m + 8*(b + 8*v): line-sharing blocks same XCD.
// Staging vectorized: dt/u/zg via bf16x8 (one 16B load = all 8 j at one l; d0 is
// 8-aligned); dbl via float4 (4 j). 22 global loads/thread (was 112 scalar).
// LDS column writes: lanes at consecutive l -> contiguous 2B -> bank-free.
// block 64.
__global__ __launch_bounds__(64) void scan_kernel(const bf16* __restrict__ dtb, const bf16* __restrict__ ub,
    const float* __restrict__ dblb, const bf16* __restrict__ xzb,
    const float* __restrict__ fAlog, const float* __restrict__ fD,
    const float* __restrict__ bAlog, const float* __restrict__ bD,
    bf16* __restrict__ yb)
{
  int fid = blockIdx.x;
  int kk2 = fid >> 8;          // 0..7  (within line-sharing group)
  int g   = fid & 255;
  int m   = g & 7;             // d-slice group
  int bv  = g >> 3;            // 0..31
  int b   = bv & 7;
  int v   = bv >> 3;           // 0..3
  int d0  = (m*8 + kk2)*8;
  int tid = threadIdx.x;
  int dd = tid & 7, qtr = tid >> 3;       // qtr in 0..7, 2 states each
  int d = d0 + dd;
  const bf16*  dt  = dtb  + (long)v*1024*512;
  const bf16*  u   = ub   + (long)v*1024*512;
  const float* dbl = dblb + (long)v*1024*48;
  const bf16*  zg  = xzb  + (long)v*1024*1024 + 512;
  const float* Alog = (v < 2) ? fAlog : bAlog;
  const float* Dp   = (v < 2) ? fD : bD;
  __shared__ __align__(16) short sdt[8][136];
  __shared__ __align__(16) short su_[8][136];
  __shared__ __align__(16) short szg[8][136];
  __shared__ __align__(16) short sB [16][136];
  __shared__ __align__(16) short sC [16][136];
  long row = (long)b*L_;
  // dt/u/zg: one bf16x8 load = all 8 j at one l (2 iterations/thread/stream)
  for (int l = tid; l < 128; l += 64){
    bf16x8v vdt = *(const bf16x8v*)&dt[(row + l)*512 + d0];
    bf16x8v vu  = *(const bf16x8v*)&u[(row + l)*512 + d0];
    bf16x8v vzg = *(const bf16x8v*)&zg[(row + l)*1024 + d0];
    #pragma unroll
    for (int j = 0; j < 8; j++){
      sdt[j][l] = vdt[j];
      su_[j][l] = vu[j];
      szg[j][l] = vzg[j];
    }
  }
  // sB/sC: float4 loads (4 j each); idx over [128 l][4 quarters] (8 iterations)
  for (int idx = tid; idx < 512; idx += 64){
    int l = idx >> 2, q = (idx & 3)*4;
    float4 vB = *(const float4*)&dbl[(row + l)*48 + 16 + q];
    float4 vC = *(const float4*)&dbl[(row + l)*48 + 32 + q];
    sB[q  ][l] = b2s(f2b(vB.x)); sB[q+1][l] = b2s(f2b(vB.y));
    sB[q+2][l] = b2s(f2b(vB.z)); sB[q+3][l] = b2s(f2b(vB.w));
    sC[q  ][l] = b2s(f2b(vC.x)); sC[q+1][l] = b2s(f2b(vC.y));
    sC[q+2][l] = b2s(f2b(vC.z)); sC[q+3][l] = b2s(f2b(vC.w));
  }
  float a2[2];
  #pragma unroll
  for (int n = 0; n < 2; n++) a2[n] = -expf(Alog[d*16 + qtr*2 + n]) * 1.44269504f;
  float Dv = Dp[d];
  float h[2];
  h[0] = 0.f; h[1] = 0.f;
  __syncthreads();
  bf16* yo = yb + (long)v*1024*512;
  for (int l0 = 0; l0 < 128; l0 += 8){
    bf16x8v dt8 = *(const bf16x8v*)&sdt[dd][l0];
    bf16x8v u8  = *(const bf16x8v*)&su_[dd][l0];
    bf16x8v zg8 = *(const bf16x8v*)&szg[dd][l0];
    bf16x8v B8[2], C8[2];
    #pragma unroll
    for (int n = 0; n < 2; n++){
      B8[n] = *(const bf16x8v*)&sB[qtr*2 + n][l0];
      C8[n] = *(const bf16x8v*)&sC[qtr*2 + n][l0];
    }
    #pragma unroll
    for (int k = 0; k < 8; k++){
      bf16 t0; *(short*)&t0 = dt8[k]; float dtv = b2f(t0);
      bf16 t1; *(short*)&t1 = u8[k];  float uv  = b2f(t1);
      bf16 t2; *(short*)&t2 = zg8[k]; float zgv = b2f(t2);
      float dtu = dtv*uv;
      float acc = 0.f;
      #pragma unroll
      for (int n = 0; n < 2; n++){
        float dA = exp2f(dtv*a2[n]);
        bf16 tb; *(short*)&tb = B8[n][k];
        bf16 tc; *(short*)&tc = C8[n][k];
        h[n] = dA*h[n] + dtu*b2f(tb);
        acc += h[n]*b2f(tc);
      }
      acc += __shfl_xor(acc, 8);
      acc += __shfl_xor(acc, 16);
      acc += __shfl_xor(acc, 32);
      if (qtr == 0)
        yo[(row + l0 + k)*512 + d] = f2b((acc + Dv*uv) * siluf(zgv));
    }
  }
}

// ---------------- LayerNorm over C: mode 1 -> bf16 concat; mode 0 -> fp32 copy -----
// grid (128, B, NV), block 256
__global__ __launch_bounds__(256) void ln_kernel(const float* __restrict__ inb, bf16* __restrict__ outb0,
    bf16* __restrict__ outb1, float* __restrict__ outf,
    const float* __restrict__ lnw, const float* __restrict__ lnb, int mode)
{
  int r = blockIdx.x, b = blockIdx.y, v = blockIdx.z, c = threadIdx.x;
  long row = (long)b*L_ + r;
  float val = inb[((long)v*1024 + row)*C_ + c];
  __shared__ float red[16];
  float s = val, s2 = val*val;
  bred2(s, s2, red);
  float m = s*(1.f/256.f), var = s2*(1.f/256.f) - m*m;
  float o = (val - m)*rsqrtf(vclamp(var))*lnw[c] + lnb[c];
  if (mode == 1){
    long frow = (long)b*L_ + (127 - r);
    if (v == 0)      outb0[row*512 + c] = f2b(o);
    else if (v == 1) outb1[row*512 + c] = f2b(o);
    else if (v == 2) outb0[frow*512 + 256 + c] = f2b(o);
    else             outb1[frow*512 + 256 + c] = f2b(o);
  } else {
    outf[((long)v*1024 + row)*C_ + c] = o;
  }
}

// ---------------- hsig(rm+rn)*clip(bn2(z2)) + gn stats; resq IN-PLACE in z2 --------
// Vectorized bf16x8 reads; packed uint2 writes; 2-register preload; one barrier.
// grid (C, B), block 256
__global__ __launch_bounds__(256) void hsig_kernel(bf16* __restrict__ z2, const float* __restrict__ rm,
    const float* __restrict__ rn, const float* __restrict__ bn2part,
    const float* __restrict__ g2, const float* __restrict__ b2,
    float* __restrict__ gnsum, float* __restrict__ gnsq)
{
  int c = blockIdx.x, b = blockIdx.y, tid = threadIdx.x;
  __shared__ float red[16];
  __shared__ float rms[128], rns[128];
  if (tid < 128){
    rms[tid] = rm[(long)(b*L_ + tid)*C_ + c];
    rns[tid] = rn[(long)(b*L_ + tid)*C_ + c];
  }
  float pa = 0.f, pb = 0.f;
  if (tid < 64){ pa = bn2part[tid*256 + c]; pb = bn2part[16384 + tid*256 + c]; }
  bred2(pa, pb, red);          // internal barriers also cover the rms/rns writes
  float mm2 = pa*(1.f/131072.f);
  float vv2 = pb*(1.f/131072.f) - mm2*mm2;
  float aa = g2[c] * rsqrtf(vclamp(vv2));
  float dd = b2[c] - mm2*aa;
  bf16* zp = z2 + ((long)(b*C_ + c))*16384;
  int j0 = (tid & 15)*8;
  int irow = tid >> 4;
  // preload collision-prone g=0,1 (p < 4096)
  bf16x8v pre0 = *(const bf16x8v*)&zp[0*2048 + tid*8];
  bf16x8v pre1 = *(const bf16x8v*)&zp[1*2048 + tid*8];
  __syncthreads();             // all preloads done before any packed write
  float s = 0.f, s2 = 0.f;
  #pragma unroll
  for (int g = 0; g < 8; g++){
    bf16x8v v8;
    if (g == 0) v8 = pre0;
    else if (g == 1) v8 = pre1;
    else v8 = *(const bf16x8v*)&zp[g*2048 + tid*8];
    int i = g*16 + irow;
    bf16 ov[4];
    #pragma unroll
    for (int k = 0; k < 8; k++){
      bf16 t; *(short*)&t = v8[k];
      float zv = b2f(t)*aa + dd;
      zv = fminf(fmaxf(zv, 0.f), 6.f);
      float gate = rms[i] + rns[j0 + k];
      gate = fminf(fmaxf(gate + 3.f, 0.f), 6.f) * (1.f/6.f);
      float t2 = gate*zv;
      s += t2; s2 += t2*t2;
      if ((k & 1) == 0) ov[k >> 1] = f2b(t2);
    }
    if ((i & 1) == 0)
      *(uint2*)&zp[(i >> 1)*64 + (tid & 15)*4] = *(const uint2*)ov;
  }
  bred2(s, s2, red);
  if (tid == 0){ atomicAdd(&gnsum[b*32 + (c >> 3)], s); atomicAdd(&gnsq[b*32 + (c >> 3)], s2); }
}

// ---------------- FUSED down-pw (swapped-MFMA epilogue, 32KB LDS) ------------------
// grid (64, B), block 256.
__global__ __launch_bounds__(256) void pwdown_fused_kernel(const bf16* __restrict__ z2,
    const float* __restrict__ gnsum, const float* __restrict__ gnsq,
    const float* __restrict__ gn_g, const float* __restrict__ gn_b,
    const bf16* __restrict__ Wb, const float* __restrict__ x,
    float* __restrict__ out, float* __restrict__ sds)
{
  int b = blockIdx.y;
  int p0 = blockIdx.x*64;
  int tid = threadIdx.x;
  __shared__ __align__(16) short Tb[16384];
  __shared__ float gA[256], gD[256];
  {
    float m = gnsum[b*32 + (tid >> 3)]*(1.f/131072.f);
    float v = gnsq[b*32 + (tid >> 3)]*(1.f/131072.f) - m*m;
    float A = rsqrtf(vclamp(v))*gn_g[tid];
    gA[tid] = A; gD[tid] = gn_b[tid] - m*A;
  }
  __syncthreads();
  {
    int pc = tid & 15, ch = tid >> 4;
    #pragma unroll
    for (int it = 0; it < 8; it++){
      int c = (ch + it*16)*2;
      const bf16* r0 = &z2[((long)(b*C_ + c))*16384 + p0 + pc*4];
      bf16x4v va = *(const bf16x4v*)r0;
      bf16x4v vb = *(const bf16x4v*)(r0 + 16384);
      float a0 = gA[c], d0 = gD[c];
      float a1 = gA[c + 1], d1 = gD[c + 1];
      #pragma unroll
      for (int k = 0; k < 4; k++){
        int p = pc*4 + k;
        bf16 h0; *(short*)&h0 = va[k];
        bf16 h1; *(short*)&h1 = vb[k];
        bf16 o0 = f2b(b2f(h0)*a0 + d0);
        bf16 o1 = f2b(b2f(h1)*a1 + d1);
        unsigned int u = ((unsigned int)(*(unsigned short*)&o1) << 16) | (unsigned int)(*(unsigned short*)&o0);
        *(unsigned int*)((char*)Tb + tswz(p, c)) = u;
      }
    }
  }
  __syncthreads();
  int wave = tid >> 6, lane = tid & 63;
  int quad = lane >> 4, l16 = lane & 15;
  f32x4v acc[4][4];
  #pragma unroll
  for (int i = 0; i < 4; i++)
    #pragma unroll
    for (int j = 0; j < 4; j++) acc[i][j] = (f32x4v){0.f, 0.f, 0.f, 0.f};
  for (int k0 = 0; k0 < 256; k0 += 32){
    int c = k0 + quad*8;
    bf16x8v a[4], bb[4];
    #pragma unroll
    for (int ms = 0; ms < 4; ms++)
      a[ms] = *(const bf16x8v*)&Wb[(wave*64 + ms*16 + l16)*C_ + c];
    #pragma unroll
    for (int ns = 0; ns < 4; ns++){
      int p = ns*16 + l16;
      bb[ns] = *(const bf16x8v*)((const char*)Tb + tswz(p, c));
    }
    #pragma unroll
    for (int ms = 0; ms < 4; ms++)
      #pragma unroll
      for (int ns = 0; ns < 4; ns++)
        acc[ms][ns] = __builtin_amdgcn_mfma_f32_16x16x32_bf16(bb[ns], a[ms], acc[ms][ns], 0, 0, 0);
  }
  #pragma unroll
  for (int ms = 0; ms < 4; ms++){
    int o = wave*64 + ms*16 + l16;
    long rowbase = ((long)(b*C_ + o))*4096 + p0;
    float sd = 0.f, sd2 = 0.f, sdx = 0.f;
    #pragma unroll
    for (int ns = 0; ns < 4; ns++){
      f32x4v v4 = acc[ms][ns];
      long base = rowbase + ns*16 + quad*4;
      *(f32x4v*)&out[base] = v4;
      float4 xv = *(const float4*)&x[base];
      sd += v4[0] + v4[1] + v4[2] + v4[3];
      sd2 += v4[0]*v4[0] + v4[1]*v4[1] + v4[2]*v4[2] + v4[3]*v4[3];
      sdx += v4[0]*xv.x + v4[1]*xv.y + v4[2]*xv.z + v4[3]*xv.w;
    }
    sd += __shfl_xor(sd, 16);  sd += __shfl_xor(sd, 32);
    sd2 += __shfl_xor(sd2, 16); sd2 += __shfl_xor(sd2, 32);
    sdx += __shfl_xor(sdx, 16); sdx += __shfl_xor(sdx, 32);
    if (quad == 0){
      int oc = (b << 8) + o;
      atomicAdd(&sds[oc], sd);
      atomicAdd(&sds[2048 + oc], sd2);
      atomicAdd(&sds[4096 + oc], sdx);
    }
  }
}

// ---------------- final: inline coeff + elementwise (float4, G13) ------------------
// out = P*out + Q*x + R, in-place on d_out. grid (C, B), block 256
__global__ __launch_bounds__(256) void final_kernel(const float* __restrict__ x,
    const float* __restrict__ sds, const float* __restrict__ sxb,
    const float* __restrict__ dbn_g, const float* __restrict__ dbn_b,
    const float* __restrict__ gn_g, const float* __restrict__ gn_b,
    float* __restrict__ out)
{
  int c = blockIdx.x, b = blockIdx.y, tid = threadIdx.x;
  __shared__ float lv[11][8];
  int g8 = (c >> 3) << 3;
  if (tid < 8){
    int cc = g8 + tid;
    float sd = 0.f, sd2 = 0.f;
    for (int bb2 = 0; bb2 < 8; bb2++){ sd += sds[bb2*256 + cc]; sd2 += sds[2048 + bb2*256 + cc]; }
    float mB = sd*(1.f/32768.f);
    float vB = sd2*(1.f/32768.f) - mB*mB;
    float ab = dbn_g[cc] * rsqrtf(vclamp(vB));
    float db = dbn_b[cc] - mB*ab;
    float inv_n = 1.f/4096.f;
    float m = sds[b*256 + cc]*inv_n, Ed2 = sds[2048 + b*256 + cc]*inv_n;
    float mx = sxb[b*256 + cc]*inv_n, Ex2 = sxb[2048 + b*256 + cc]*inv_n;
    float Edx = sds[4096 + b*256 + cc]*inv_n;
    float Ev = ab*m + db;
    float Ev2 = ab*ab*Ed2 + 2.f*ab*db*m + db*db;
    lv[0][tid] = ab; lv[1][tid] = db; lv[2][tid] = m; lv[3][tid] = Ed2;
    lv[4][tid] = mx; lv[5][tid] = Ex2; lv[6][tid] = Edx; lv[7][tid] = Ev; lv[8][tid] = Ev2;
  }
  __syncthreads();
  if (tid < 8){
    float m1 = 0.f, q1 = 0.f;
    for (int k = 0; k < 8; k++){ m1 += lv[7][k]; q1 += lv[8][k]; }
    m1 *= 0.125f; q1 *= 0.125f;
    int cc = g8 + tid;
    float inv1 = rsqrtf(vclamp(q1 - m1*m1));
    float A1 = inv1*gn_g[cc];
    float D1 = gn_b[cc] - m1*A1;
    float ab = lv[0][tid], db = lv[1][tid];
    float m = lv[2][tid], Ed2 = lv[3][tid], mx = lv[4][tid], Ex2 = lv[5][tid], Edx = lv[6][tid];
    float al = A1*ab;
    float be = A1*db + D1;
    float Et = al*m + be + mx;
    float Et2 = al*al*Ed2 + 2.f*al*be*m + be*be + 2.f*al*Edx + 2.f*be*mx + Ex2;
    lv[9][tid] = Et; lv[10][tid] = Et2; lv[0][tid] = al; lv[1][tid] = be;
  }
  __syncthreads();
  float m2 = 0.f, q2 = 0.f;
  for (int k = 0; k < 8; k++){ m2 += lv[9][k]; q2 += lv[10][k]; }
  m2 *= 0.125f; q2 *= 0.125f;
  float G = rsqrtf(vclamp(q2 - m2*m2))*gn_g[c];
  float P = G*lv[0][c & 7];
  float Q = G;
  float R = G*(lv[1][c & 7] - m2) + gn_b[c];
  long base = ((long)(b*C_ + c))*1024;      // float4 units
  const float4* x4 = (const float4*)x;
  float4* o4 = (float4*)out;
  #pragma unroll
  for (int it = 0; it < 4; it++){
    long idx = base + it*256 + tid;
    float4 o = o4[idx];
    float4 xv = x4[idx];
    o.x = P*o.x + Q*xv.x + R;
    o.y = P*o.y + Q*xv.y + R;
    o.z = P*o.z + Q*xv.z + R;
    o.w = P*o.w + Q*xv.w + R;
    o4[idx] = o;
  }
}

extern "C" void kernel_launch(void* const* d_in, const int* in_sizes, int n_in,
                              void* d_out, int out_size, void* d_ws, size_t ws_size,
                              hipStream_t stream)
{
  (void)in_sizes; (void)n_in; (void)out_size; (void)ws_size;
  // ALL inputs/outputs are float32.
  const float* x         = (const float*)d_in[0];
  const float* pos       = (const float*)d_in[1];
  const float* ln_w      = (const float*)d_in[2];
  const float* ln_b      = (const float*)d_in[3];
  const float* proj_w    = (const float*)d_in[4];
  const float* proj_b    = (const float*)d_in[5];
  const float* up_dw_w   = (const float*)d_in[6];
  const float* up_bn1_g  = (const float*)d_in[7];
  const float* up_bn1_b  = (const float*)d_in[8];
  const float* up_pw_w   = (const float*)d_in[9];
  const float* up_bn2_g  = (const float*)d_in[10];
  const float* up_bn2_b  = (const float*)d_in[11];
  const float* down_pw_w = (const float*)d_in[12];
  const float* down_bn_g = (const float*)d_in[13];
  const float* down_bn_b = (const float*)d_in[14];
  const float* gn_g      = (const float*)d_in[15];
  const float* gn_b      = (const float*)d_in[16];
  const float* f_in_w    = (const float*)d_in[17];
  const float* f_conv_w  = (const float*)d_in[18];
  const float* f_conv_b  = (const float*)d_in[19];
  const float* f_xproj_w = (const float*)d_in[20];
  const float* f_dt_w    = (const float*)d_in[21];
  const float* f_dt_b    = (const float*)d_in[22];
  const float* f_Alog    = (const float*)d_in[23];
  const float* f_D       = (const float*)d_in[24];
  const float* f_out_w   = (const float*)d_in[25];
  const float* b_in_w    = (const float*)d_in[26];
  const float* b_conv_w  = (const float*)d_in[27];
  const float* b_conv_b  = (const float*)d_in[28];
  const float* b_xproj_w = (const float*)d_in[29];
  const float* b_dt_w    = (const float*)d_in[30];
  const float* b_dt_b    = (const float*)d_in[31];
  const float* b_Alog    = (const float*)d_in[32];
  const float* b_D       = (const float*)d_in[33];
  const float* b_out_w   = (const float*)d_in[34];

  // ======== workspace layout ========
  char* sb = (char*)d_ws;
  float* statz  = (float*)(sb);               // 1536 f [zeroed]: bn1(512) unused(512) gn(512)
  float* sds    = (float*)(sb + 6144);        // 6144 f [zeroed]: sd | sd2 | sdx (b*256+c)
  float* bn2part= (float*)(sb + 32768);       // 32768 f [zeroed]: [64][256] sum | sq
  float* sxb    = (float*)(sb + 184320);      // 4096 f: sum x | sum x^2 (b*256+c)
  float* rmrn  = (float*)(sb + 1*MB);        // 2MB: 2 x (1024,256)
  bf16*  Wbbuf = (bf16*)(sb + 3*MB);         // 128KB: up_pw_w bf16
  bf16*  Wb2buf= (bf16*)(sb + 3*MB + 262144);// 128KB: down_pw_w bf16
  bf16*  Wpb   = (bf16*)(sb + 3*MB + 524288);// 256KB: proj_w bf16
  char* big = sb + 4*MB;
  float* pool4  = (float*)(big + 0*MB);      // 2 MB
  bf16*  hbufb  = (bf16*)(big + 2*MB);       // 2 MB: 4 x (B*L,C) bf16
  bf16*  Wif    = (bf16*)(big + 4*MB);       // 512KB: f_in_w bf16
  bf16*  Wib2   = (bf16*)(big + 4*MB + 524288); // 512KB: b_in_w bf16
  bf16*  Wxf    = (bf16*)(big + 5*MB);           // 48KB: f_xproj_w bf16
  bf16*  Wxb    = (bf16*)(big + 5*MB + 65536);   // 48KB: b_xproj_w bf16
  bf16*  Wof    = (bf16*)(big + 5*MB + 131072);  // 256KB: f_out_w bf16
  bf16*  Wob    = (bf16*)(big + 5*MB + 393216);  // 256KB: b_out_w bf16
  bf16*  xzbuf  = (bf16*)(big + 6*MB);       // 8 MB: 4 x (1024,1024) bf16
  bf16*  ubuf   = (bf16*)(big + 22*MB);      // 4 MB: 4 x (1024,512) bf16
  float* dblbuf = (float*)(big + 30*MB);     // 768 KB
  bf16*  dtbuf  = (bf16*)(big + 31*MB);      // 4 MB: 4 x (1024,512) bf16
  bf16*  ybuf   = (bf16*)(big + 39*MB);      // 4 MB: 4 x (1024,512) bf16
  float* mout   = (float*)(big + 47*MB);     // 4 MB
  bf16*  cbufb  = (bf16*)(big + 51*MB);      // 2 MB: 2 x (1024,512) bf16
  float* respre = (float*)(big + 55*MB);     // 2 MB  (ends at 57MB < 64MB)
  bf16*  z1buf  = (bf16*)(big);              // 64 MiB bf16, c-major (phase 2)
  bf16*  z2buf  = (bf16*)(big);              // 64 MiB bf16 (in-place over z1)
  float* dbuf   = (float*)d_out;             // 32 MB fp32 (phase 3)

  float* bn1sum = statz;        float* bn1sq = statz + 256;
  float* gnsum  = statz + 1024; float* gnsq  = statz + 1280;
  float* pcolmax = pool4;
  float* pcolmin = pool4 + 131072;
  float* prowmax = pool4 + 262144;
  float* prowmin = pool4 + 393216;

  hipMemsetAsync(statz, 0, 163840, stream);   // statz + sds + bn2part

  // ---- all weight converts in one launch ----
  wcvt_all_kernel<<<dim3(256, 9), 256, 0, stream>>>(
      f_in_w, b_in_w, f_xproj_w, b_xproj_w, f_out_w, b_out_w, proj_w, up_pw_w, down_pw_w,
      Wif, Wib2, Wxf, Wxb, Wof, Wob, Wpb, Wbbuf, Wb2buf);

  // ---- phase 1: pooling + LN + mamba x4 (f/b x max/min) -> rmrn ----
  pool1_kernel<<<dim3(256, 8), 64, 0, stream>>>(x, pos, pcolmax, pcolmin, prowmax, prowmin, sxb);
  pool2_kernel<<<dim3(128, 8), 256, 0, stream>>>(pcolmax, pcolmin, prowmax, prowmin, ln_w, ln_b, hbufb);
  inproj_mfma_kernel<<<dim3(16, 4, 4), 256, 0, stream>>>(hbufb, Wif, Wib2, xzbuf);
  conv1d_kernel<<<dim3(128, 8, 4), 512, 0, stream>>>(xzbuf, f_conv_w, f_conv_b, b_conv_w, b_conv_b, ubuf);
  xproj_mfma_kernel<<<dim3(4, 4), 256, 0, stream>>>(ubuf, Wxf, Wxb, dblbuf);
  gemm_kernel<<<dim3(8, 16, 4), 256, 0, stream>>>(dblbuf, 49152, 48, f_dt_w, b_dt_w, f_dt_b, b_dt_b, 2,
                                                  (float*)dtbuf, 524288, 512, 1024, 512, 16, 3);
  scan_kernel<<<2048, 64, 0, stream>>>(dtbuf, ubuf, dblbuf, xzbuf, f_Alog, f_D, b_Alog, b_D, ybuf);
  outproj_mfma_kernel<<<dim3(4, 4, 4), 256, 0, stream>>>(ybuf, Wof, Wob, mout);
  ln_kernel<<<dim3(128, 8, 4), 256, 0, stream>>>(mout, cbufb, cbufb + 524288, nullptr, ln_w, ln_b, 1);
  pj_mfma_kernel<<<dim3(4, 4, 2), 256, 0, stream>>>(cbufb, Wpb, proj_b, respre);
  ln_kernel<<<dim3(128, 8, 2), 256, 0, stream>>>(respre, nullptr, nullptr, rmrn, ln_w, ln_b, 0);

  // ---- phase 2: z path (dwconvT -> bn1 -> relu -> pw -> bn2 partials, fused) ----
  dwz1_kernel<<<2048, 256, 0, stream>>>(x, up_dw_w, z1buf, bn1sum, bn1sq);
  pwz_fused_kernel<<<dim3(256, 8), 256, 0, stream>>>(z1buf, bn1sum, bn1sq, up_bn1_g, up_bn1_b,
                                                     Wbbuf, z2buf, bn2part);

  // ---- phase 3: merge + tail ----
  hsig_kernel<<<dim3(256, 8), 256, 0, stream>>>(z2buf, rmrn, rmrn + 262144, bn2part,
                                                up_bn2_g, up_bn2_b, gnsum, gnsq);
  pwdown_fused_kernel<<<dim3(64, 8), 256, 0, stream>>>(z2buf, gnsum, gnsq, gn_g, gn_b,
                                                       Wb2buf, x, dbuf, sds);
  final_kernel<<<dim3(256, 8), 256, 0, stream>>>(x, sds, sxb, down_bn_g, down_bn_b, gn_g, gn_b,
                                                 (float*)d_out);
}

// Round 11
// 445.099 us; speedup vs baseline: 1.0349x; 1.0349x over previous
//
#include <hip/hip_runtime.h>
#include <hip/hip_bf16.h>

typedef __hip_bfloat16 bf16;
typedef __attribute__((ext_vector_type(8))) short bf16x8v;
typedef __attribute__((ext_vector_type(4))) short bf16x4v;
typedef __attribute__((ext_vector_type(4))) float f32x4v;

#define B_ 8
#define C_ 256
#define L_ 128
#define MB 1048576UL

__device__ inline float b2f(bf16 v){ return __bfloat162float(v); }
__device__ inline bf16 f2b(float v){ return __float2bfloat16(v); }
__device__ inline short b2s(bf16 v){ return *(short*)&v; }
__device__ inline float siluf(float x){ return x / (1.f + expf(-x)); }
__device__ inline float softplusf(float x){ return (x > 20.f) ? x : log1pf(expf(x)); }
__device__ inline float vclamp(float v){ return fmaxf(v, 0.f) + 1e-5f; }

// block = 256 threads (4 waves). red must hold >=16 floats.
__device__ inline void bred2(float& a, float& b, float* red){
  #pragma unroll
  for (int m = 1; m < 64; m <<= 1){ a += __shfl_xor(a, m); b += __shfl_xor(b, m); }
  int tid = threadIdx.x, wave = tid >> 6, lane = tid & 63;
  __syncthreads();                       // protect red[] reuse across calls
  if (lane == 0){ red[wave] = a; red[8 + wave] = b; }
  __syncthreads();
  a = red[0] + red[1] + red[2] + red[3];
  b = red[8] + red[9] + red[10] + red[11];
}

// LDS transpose-tile swizzle: 64p x 256c bf16 (32KB linear).
// s(p) = ((p ^ (p>>2)) & 7) << 4 injects BOTH p bits 0-2 (read lanes: l16)
// and p bits 2-4 (write lanes: pc) into byte bits 4-6. 2 lanes/bank both ways (free).
__device__ inline int tswz(int p, int c){
  return (p*512 + c*2) ^ (((p ^ (p >> 2)) & 7) << 4);
}

// ---------------- pooling step 1: row/col max/min + argmax + pos-embed -------------
// float4 global loads (G13); scalar LDS writes keep the [65]-pad conflict-free reads.
// grid (C, B), block 64
__global__ __launch_bounds__(64) void pool1_kernel(const float* __restrict__ x, const float* __restrict__ pos,
    float* __restrict__ pcolmax, float* __restrict__ pcolmin,
    float* __restrict__ prowmax, float* __restrict__ prowmin, float* __restrict__ sxb)
{
  int c = blockIdx.x, b = blockIdx.y, t = threadIdx.x;
  __shared__ float xs[64][65];
  const float* xp = x + ((long)(b*C_ + c))*4096;
  const float4* xp4 = (const float4*)xp;
  #pragma unroll
  for (int q = 0; q < 16; q++){
    float4 v = xp4[q*64 + t];
    int e = q*64 + t;
    int i = e >> 4, cc = (e & 15) << 2;
    xs[i][cc] = v.x; xs[i][cc+1] = v.y; xs[i][cc+2] = v.z; xs[i][cc+3] = v.w;
  }
  __syncthreads();
  // jax.image.resize 'linear' 16->64: half-pixel coords, edge clamp
  float tt = 0.25f*(float)t - 0.375f;
  const float* pp = pos + c*16;
  float pe;
  if (tt <= 0.f) pe = pp[0];
  else if (tt >= 15.f) pe = pp[15];
  else { int f = (int)floorf(tt); float w = tt - (float)f; pe = pp[f]*(1.f - w) + pp[f+1]*w; }
  float vmax = -1e30f, vmin = 1e30f; int amax = 0, amin = 0;
  for (int j = 0; j < 64; j++){
    float v = xs[t][j];
    if (v > vmax){ vmax = v; amax = j; }
    if (v < vmin){ vmin = v; amin = j; }
  }
  long o = (long)(b*64 + t)*C_ + c;
  prowmax[o] = vmax + pe + (float)amax;
  prowmin[o] = vmin + pe + (float)amin;
  vmax = -1e30f; vmin = 1e30f; amax = 0; amin = 0;
  float sx = 0.f, sx2 = 0.f;
  for (int i = 0; i < 64; i++){
    float v = xs[i][t];
    if (v > vmax){ vmax = v; amax = i; }
    if (v < vmin){ vmin = v; amin = i; }
    sx += v; sx2 += v*v;
  }
  pcolmax[o] = vmax + pe + (float)amax;
  pcolmin[o] = vmin + pe + (float)amin;
  #pragma unroll
  for (int m = 1; m < 64; m <<= 1){ sx += __shfl_xor(sx, m); sx2 += __shfl_xor(sx2, m); }
  if (t == 0){ sxb[(b << 8) + c] = sx; sxb[2048 + (b << 8) + c] = sx2; }
}

// ---------------- pooling step 2: LN over channels, write 4 mamba inputs (bf16) ----
// grid (128, B), block 256
__global__ __launch_bounds__(256) void pool2_kernel(const float* __restrict__ pcolmax, const float* __restrict__ pcolmin,
    const float* __restrict__ prowmax, const float* __restrict__ prowmin,
    const float* __restrict__ lnw, const float* __restrict__ lnb, bf16* __restrict__ hbuf)
{
  int r = blockIdx.x, b = blockIdx.y, c = threadIdx.x;
  __shared__ float red[16];
  int p = r & 63;
  long src = (long)(b*64 + p)*C_ + c;
  float vmax = (r < 64) ? pcolmax[src] : prowmax[src];
  float vmin = (r < 64) ? pcolmin[src] : prowmin[src];
  float gw = lnw[c], gb = lnb[c];
  long row = (long)b*L_ + r, frow = (long)b*L_ + (127 - r);
  float s = vmax, s2 = vmax*vmax;
  bred2(s, s2, red);
  float m = s*(1.f/256.f), var = s2*(1.f/256.f) - m*m;
  float o = (vmax - m)*rsqrtf(vclamp(var))*gw + gb;
  hbuf[0*262144 + row*C_ + c]  = f2b(o);
  hbuf[2*262144 + frow*C_ + c] = f2b(o);
  s = vmin; s2 = vmin*vmin;
  bred2(s, s2, red);
  m = s*(1.f/256.f); var = s2*(1.f/256.f) - m*m;
  o = (vmin - m)*rsqrtf(vclamp(var))*gw + gb;
  hbuf[1*262144 + row*C_ + c]  = f2b(o);
  hbuf[3*262144 + frow*C_ + c] = f2b(o);
}

// ---------------- z1raw = dwconvT(x) as bf16 + bn1 stats (one pass) ----------------
// 2x2 output-quad specialization (bit-exact). grid (B*C), block 256.
__global__ __launch_bounds__(256) void dwz1_kernel(const float* __restrict__ x, const float* __restrict__ dw,
    bf16* __restrict__ z1, float* __restrict__ bn1sum, float* __restrict__ bn1sq)
{
  int bc = blockIdx.x; int c = bc & 255;
  int tid = threadIdx.x;
  __shared__ __align__(16) float xs[4096];
  const float4* xp4 = (const float4*)(x + (long)bc*4096);
  #pragma unroll
  for (int q = 0; q < 4; q++)
    *(float4*)&xs[(q*256 + tid)*4] = xp4[q*256 + tid];
  float w[9];
  #pragma unroll
  for (int q = 0; q < 9; q++) w[q] = dw[c*9 + q];
  __syncthreads();
  bf16* zp = z1 + (long)bc*16384;
  float s = 0.f, s2 = 0.f;
  for (int it = 0; it < 16; it++){
    int q = it*256 + tid;            // quad id 0..4095
    int a = q >> 6, bq = q & 63;
    int a1 = (a < 63) ? a + 1 : 63;
    int b1 = (bq < 63) ? bq + 1 : 63;
    float XA = xs[a*64 + bq];
    float XB = xs[a*64 + b1];
    float XC = xs[a1*64 + bq];
    float XD = xs[a1*64 + b1];
    float w3e = (bq < 63) ? w[3] : 0.f;
    float w6e = (bq < 63) ? w[6] : 0.f;
    float w1e = (a < 63) ? w[1] : 0.f;
    float w2e = (a < 63) ? w[2] : 0.f;
    float w0e = (a < 63 && bq < 63) ? w[0] : 0.f;
    float o00 = w[4]*XA; o00 += 0.f*XB; o00 += 0.f*XC; o00 += 0.f*XD;
    float o01 = w[5]*XA; o01 += w3e*XB; o01 += 0.f*XC; o01 += 0.f*XD;
    float o10 = w[7]*XA; o10 += 0.f*XB; o10 += w1e*XC; o10 += 0.f*XD;
    float o11 = w[8]*XA; o11 += w6e*XB; o11 += w2e*XC; o11 += w0e*XD;
    bf16 r0[2] = {f2b(o00), f2b(o01)};
    bf16 r1[2] = {f2b(o10), f2b(o11)};
    *(unsigned int*)&zp[(2*a)*128 + 2*bq]     = *(const unsigned int*)r0;
    *(unsigned int*)&zp[(2*a + 1)*128 + 2*bq] = *(const unsigned int*)r1;
    s += o00; s2 += o00*o00;
    s += o01; s2 += o01*o01;
    s += o10; s2 += o10*o10;
    s += o11; s2 += o11*o11;
  }
  __shared__ float red[16];
  bred2(s, s2, red);
  if (tid == 0){ atomicAdd(&bn1sum[c], s); atomicAdd(&bn1sq[c], s2); }
}

// ---------------- all fp32 -> bf16 weight converts in ONE launch -------------------
// grid (256, 9), block 256; 4 elems/thread.
__global__ __launch_bounds__(256) void wcvt_all_kernel(
    const float* __restrict__ s0, const float* __restrict__ s1, const float* __restrict__ s2,
    const float* __restrict__ s3, const float* __restrict__ s4, const float* __restrict__ s5,
    const float* __restrict__ s6, const float* __restrict__ s7, const float* __restrict__ s8,
    bf16* __restrict__ d0, bf16* __restrict__ d1, bf16* __restrict__ d2,
    bf16* __restrict__ d3, bf16* __restrict__ d4, bf16* __restrict__ d5,
    bf16* __restrict__ d6, bf16* __restrict__ d7, bf16* __restrict__ d8)
{
  int seg = blockIdx.y;
  const float* s; bf16* d; int n;
  switch (seg){
    case 0: s = s0; d = d0; n = 262144; break;
    case 1: s = s1; d = d1; n = 262144; break;
    case 2: s = s2; d = d2; n = 24576;  break;
    case 3: s = s3; d = d3; n = 24576;  break;
    case 4: s = s4; d = d4; n = 131072; break;
    case 5: s = s5; d = d5; n = 131072; break;
    case 6: s = s6; d = d6; n = 131072; break;
    case 7: s = s7; d = d7; n = 65536;  break;
    default: s = s8; d = d8; n = 65536; break;
  }
  long i = ((long)blockIdx.x*256 + threadIdx.x)*4;
  if (i >= n) return;
  float4 v = *(const float4*)&s[i];
  bf16 o[4] = {f2b(v.x), f2b(v.y), f2b(v.z), f2b(v.w)};
  *(uint2*)&d[i] = *(const uint2*)o;
}

// ---------------- FUSED up-pw (swapped-MFMA epilogue, aa/dd LDS table) -------------
// grid (256, B), block 256.
__global__ __launch_bounds__(256) void pwz_fused_kernel(const bf16* __restrict__ z1,
    const float* __restrict__ bn1sum, const float* __restrict__ bn1sq,
    const float* __restrict__ g1, const float* __restrict__ b1,
    const bf16* __restrict__ Wb, bf16* __restrict__ z2,
    float* __restrict__ bn2part)
{
  int b = blockIdx.y;
  int p0 = blockIdx.x*64;
  int tid = threadIdx.x;
  __shared__ __align__(16) short Tb[16384];   // 64p x 256c bf16, tswz layout
  __shared__ float aa[256], dd[256];
  {
    float m = bn1sum[tid]*(1.f/131072.f);
    float v = bn1sq[tid]*(1.f/131072.f) - m*m;
    float a = g1[tid]*rsqrtf(vclamp(v));
    aa[tid] = a; dd[tid] = b1[tid] - m*a;
  }
  __syncthreads();
  {
    int pc = tid & 15, ch = tid >> 4;
    #pragma unroll
    for (int it = 0; it < 8; it++){
      int c = (ch + it*16)*2;
      const bf16* r0 = &z1[((long)(b*C_ + c))*16384 + p0 + pc*4];
      bf16x4v va = *(const bf16x4v*)r0;
      bf16x4v vb = *(const bf16x4v*)(r0 + 16384);
      float a0 = aa[c], d0 = dd[c], a1 = aa[c+1], d1 = dd[c+1];
      #pragma unroll
      for (int k = 0; k < 4; k++){
        int p = pc*4 + k;
        bf16 h0; *(short*)&h0 = va[k];
        bf16 h1; *(short*)&h1 = vb[k];
        bf16 o0 = f2b(fmaxf(b2f(h0)*a0 + d0, 0.f));
        bf16 o1 = f2b(fmaxf(b2f(h1)*a1 + d1, 0.f));
        unsigned int u = ((unsigned int)(*(unsigned short*)&o1) << 16) | (unsigned int)(*(unsigned short*)&o0);
        *(unsigned int*)((char*)Tb + tswz(p, c)) = u;
      }
    }
  }
  __syncthreads();
  int wave = tid >> 6, lane = tid & 63;
  int quad = lane >> 4, l16 = lane & 15;
  f32x4v acc[4][4];
  #pragma unroll
  for (int i = 0; i < 4; i++)
    #pragma unroll
    for (int j = 0; j < 4; j++) acc[i][j] = (f32x4v){0.f, 0.f, 0.f, 0.f};
  for (int k0 = 0; k0 < 256; k0 += 32){
    int c = k0 + quad*8;
    bf16x8v a[4], bb[4];
    #pragma unroll
    for (int ms = 0; ms < 4; ms++)
      a[ms] = *(const bf16x8v*)&Wb[(wave*64 + ms*16 + l16)*C_ + c];
    #pragma unroll
    for (int ns = 0; ns < 4; ns++){
      int p = ns*16 + l16;
      bb[ns] = *(const bf16x8v*)((const char*)Tb + tswz(p, c));
    }
    // swapped operands: acc[ms][ns] holds rows p = ns*16+quad*4+r, col o-sub = l16
    #pragma unroll
    for (int ms = 0; ms < 4; ms++)
      #pragma unroll
      for (int ns = 0; ns < 4; ns++)
        acc[ms][ns] = __builtin_amdgcn_mfma_f32_16x16x32_bf16(bb[ns], a[ms], acc[ms][ns], 0, 0, 0);
  }
  int slot = (blockIdx.x & 7) | (b << 3);
  #pragma unroll
  for (int ms = 0; ms < 4; ms++){
    int o = wave*64 + ms*16 + l16;          // this lane's output channel
    long rowbase = ((long)(b*C_ + o))*16384 + p0;
    float s = 0.f, s2 = 0.f;
    #pragma unroll
    for (int ns = 0; ns < 4; ns++){
      bf16 ov[4];
      #pragma unroll
      for (int r = 0; r < 4; r++){
        bf16 bv = f2b(acc[ms][ns][r]);
        ov[r] = bv;
        float vv = b2f(bv);
        s += vv; s2 += vv*vv;
      }
      *(uint2*)&z2[rowbase + ns*16 + quad*4] = *(const uint2*)ov;
    }
    s += __shfl_xor(s, 16);  s += __shfl_xor(s, 32);
    s2 += __shfl_xor(s2, 16); s2 += __shfl_xor(s2, 32);
    if (quad == 0){
      atomicAdd(&bn2part[slot*256 + o], s);
      atomicAdd(&bn2part[16384 + slot*256 + o], s2);
    }
  }
}

// ---------------- in_proj GEMM on MFMA (swapped epilogue): xz = hb @ Wi^T ----------
// M=1024, N=1024, K=256, bf16 out. grid (16, 4, 4), block 256.
__global__ __launch_bounds__(256) void inproj_mfma_kernel(const bf16* __restrict__ hb,
    const bf16* __restrict__ Wif, const bf16* __restrict__ Wib2, bf16* __restrict__ xz)
{
  int v = blockIdx.z;
  int m0 = blockIdx.y*256, n0 = blockIdx.x*64;
  const bf16* A = hb + (long)v*262144;
  const bf16* W = (v >= 2) ? Wib2 : Wif;
  bf16* out = xz + (long)v*1048576;
  int tid = threadIdx.x;
  int wave = tid >> 6, lane = tid & 63;
  int quad = lane >> 4, l16 = lane & 15;
  f32x4v acc[4][4];
  #pragma unroll
  for (int i = 0; i < 4; i++)
    #pragma unroll
    for (int j = 0; j < 4; j++) acc[i][j] = (f32x4v){0.f, 0.f, 0.f, 0.f};
  for (int k0 = 0; k0 < 256; k0 += 32){
    int c = k0 + quad*8;
    bf16x8v a[4], bb[4];
    #pragma unroll
    for (int ms = 0; ms < 4; ms++)
      a[ms] = *(const bf16x8v*)&A[(long)(m0 + wave*64 + ms*16 + l16)*256 + c];
    #pragma unroll
    for (int ns = 0; ns < 4; ns++)
      bb[ns] = *(const bf16x8v*)&W[(long)(n0 + ns*16 + l16)*256 + c];
    #pragma unroll
    for (int ms = 0; ms < 4; ms++)
      #pragma unroll
      for (int ns = 0; ns < 4; ns++)
        acc[ms][ns] = __builtin_amdgcn_mfma_f32_16x16x32_bf16(bb[ns], a[ms], acc[ms][ns], 0, 0, 0);
  }
  #pragma unroll
  for (int ms = 0; ms < 4; ms++){
    int m = m0 + wave*64 + ms*16 + l16;
    #pragma unroll
    for (int ns = 0; ns < 4; ns++){
      bf16 ov[4];
      #pragma unroll
      for (int r = 0; r < 4; r++) ov[r] = f2b(acc[ms][ns][r]);
      *(uint2*)&out[(long)m*1024 + n0 + ns*16 + quad*4] = *(const uint2*)ov;
    }
  }
}

// ---------------- x_proj GEMM on MFMA (swapped epilogue) ---------------------------
// M=1024, N=48, K=512. grid (4 mtile, 4 v), block 256.
__global__ __launch_bounds__(256) void xproj_mfma_kernel(const bf16* __restrict__ ub,
    const bf16* __restrict__ Wxf, const bf16* __restrict__ Wxb, float* __restrict__ dblb)
{
  int v = blockIdx.y;
  int m0 = blockIdx.x*256;
  const bf16* A = ub + (long)v*524288;
  const bf16* W = (v >= 2) ? Wxb : Wxf;
  float* out = dblb + (long)v*49152;
  int tid = threadIdx.x;
  int wave = tid >> 6, lane = tid & 63;
  int quad = lane >> 4, l16 = lane & 15;
  f32x4v acc[4][3];
  #pragma unroll
  for (int i = 0; i < 4; i++)
    #pragma unroll
    for (int j = 0; j < 3; j++) acc[i][j] = (f32x4v){0.f, 0.f, 0.f, 0.f};
  for (int k0 = 0; k0 < 512; k0 += 32){
    int c = k0 + quad*8;
    bf16x8v a[4], bb[3];
    #pragma unroll
    for (int ms = 0; ms < 4; ms++)
      a[ms] = *(const bf16x8v*)&A[(long)(m0 + wave*64 + ms*16 + l16)*512 + c];
    #pragma unroll
    for (int ns = 0; ns < 3; ns++)
      bb[ns] = *(const bf16x8v*)&W[(long)(ns*16 + l16)*512 + c];
    #pragma unroll
    for (int ms = 0; ms < 4; ms++)
      #pragma unroll
      for (int ns = 0; ns < 3; ns++)
        acc[ms][ns] = __builtin_amdgcn_mfma_f32_16x16x32_bf16(bb[ns], a[ms], acc[ms][ns], 0, 0, 0);
  }
  #pragma unroll
  for (int ms = 0; ms < 4; ms++){
    int m = m0 + wave*64 + ms*16 + l16;
    #pragma unroll
    for (int ns = 0; ns < 3; ns++)
      *(f32x4v*)&out[(long)m*48 + ns*16 + quad*4] = acc[ms][ns];
  }
}

// ---------------- out_proj GEMM on MFMA (swapped epilogue) -------------------------
// M=1024, N=256, K=512. grid (4 ntile, 4 mtile, 4 v), block 256.
__global__ __launch_bounds__(256) void outproj_mfma_kernel(const bf16* __restrict__ yb,
    const bf16* __restrict__ Wof, const bf16* __restrict__ Wob, float* __restrict__ mo)
{
  int v = blockIdx.z;
  int m0 = blockIdx.y*256, n0 = blockIdx.x*64;
  const bf16* A = yb + (long)v*524288;
  const bf16* W = (v >= 2) ? Wob : Wof;
  float* out = mo + (long)v*262144;
  int tid = threadIdx.x;
  int wave = tid >> 6, lane = tid & 63;
  int quad = lane >> 4, l16 = lane & 15;
  f32x4v acc[4][4];
  #pragma unroll
  for (int i = 0; i < 4; i++)
    #pragma unroll
    for (int j = 0; j < 4; j++) acc[i][j] = (f32x4v){0.f, 0.f, 0.f, 0.f};
  for (int k0 = 0; k0 < 512; k0 += 32){
    int c = k0 + quad*8;
    bf16x8v a[4], bb[4];
    #pragma unroll
    for (int ms = 0; ms < 4; ms++)
      a[ms] = *(const bf16x8v*)&A[(long)(m0 + wave*64 + ms*16 + l16)*512 + c];
    #pragma unroll
    for (int ns = 0; ns < 4; ns++)
      bb[ns] = *(const bf16x8v*)&W[(long)(n0 + ns*16 + l16)*512 + c];
    #pragma unroll
    for (int ms = 0; ms < 4; ms++)
      #pragma unroll
      for (int ns = 0; ns < 4; ns++)
        acc[ms][ns] = __builtin_amdgcn_mfma_f32_16x16x32_bf16(bb[ns], a[ms], acc[ms][ns], 0, 0, 0);
  }
  #pragma unroll
  for (int ms = 0; ms < 4; ms++){
    int m = m0 + wave*64 + ms*16 + l16;
    #pragma unroll
    for (int ns = 0; ns < 4; ns++)
      *(f32x4v*)&out[(long)m*256 + n0 + ns*16 + quad*4] = acc[ms][ns];
  }
}

// ---------------- proj GEMM on MFMA (swapped epilogue, +bias) ----------------------
// M=1024, N=256, K=512, z=2. grid (4 ntile, 4 mtile, 2), block 256.
__global__ __launch_bounds__(256) void pj_mfma_kernel(const bf16* __restrict__ cb,
    const bf16* __restrict__ Wp, const float* __restrict__ pb, float* __restrict__ rp)
{
  int z = blockIdx.z;
  int m0 = blockIdx.y*256, n0 = blockIdx.x*64;
  const bf16* A = cb + (long)z*524288;
  float* out = rp + (long)z*262144;
  int tid = threadIdx.x;
  int wave = tid >> 6, lane = tid & 63;
  int quad = lane >> 4, l16 = lane & 15;
  f32x4v acc[4][4];
  #pragma unroll
  for (int i = 0; i < 4; i++)
    #pragma unroll
    for (int j = 0; j < 4; j++) acc[i][j] = (f32x4v){0.f, 0.f, 0.f, 0.f};
  for (int k0 = 0; k0 < 512; k0 += 32){
    int c = k0 + quad*8;
    bf16x8v a[4], bb[4];
    #pragma unroll
    for (int ms = 0; ms < 4; ms++)
      a[ms] = *(const bf16x8v*)&A[(long)(m0 + wave*64 + ms*16 + l16)*512 + c];
    #pragma unroll
    for (int ns = 0; ns < 4; ns++)
      bb[ns] = *(const bf16x8v*)&Wp[(long)(n0 + ns*16 + l16)*512 + c];
    #pragma unroll
    for (int ms = 0; ms < 4; ms++)
      #pragma unroll
      for (int ns = 0; ns < 4; ns++)
        acc[ms][ns] = __builtin_amdgcn_mfma_f32_16x16x32_bf16(bb[ns], a[ms], acc[ms][ns], 0, 0, 0);
  }
  #pragma unroll
  for (int ns = 0; ns < 4; ns++){
    float4 pbv = *(const float4*)&pb[n0 + ns*16 + quad*4];
    #pragma unroll
    for (int ms = 0; ms < 4; ms++){
      int m = m0 + wave*64 + ms*16 + l16;
      f32x4v vv = acc[ms][ns];
      vv[0] += pbv.x; vv[1] += pbv.y; vv[2] += pbv.z; vv[3] += pbv.w;
      *(f32x4v*)&out[(long)m*256 + n0 + ns*16 + quad*4] = vv;
    }
  }
}

// ---------------- generic GEMM (dt-proj only; act==3 -> softplus + bf16 store) -----
// grid ((N+63)/64, (M+63)/64, nbatch), block 256
__global__ __launch_bounds__(256) void gemm_kernel(
  const float* __restrict__ Abase, long sA, int lda,
  const float* __restrict__ W0, const float* __restrict__ W1,
  const float* __restrict__ bias0, const float* __restrict__ bias1, int wsplit,
  float* __restrict__ Cbase, long sC, int ldc,
  int M, int N, int K, int act)
{
  int z = blockIdx.z;
  const float* A = Abase + (long)z*sA;
  const float* W = (z >= wsplit) ? W1 : W0;
  const float* bias = (z >= wsplit) ? bias1 : bias0;
  int m0 = blockIdx.y*64, n0 = blockIdx.x*64;
  __shared__ __align__(16) float As[16][68];
  __shared__ __align__(16) float Ws[16][68];
  int tid = threadIdx.x, tx = tid & 15, ty = tid >> 4;
  float acc[4][4] = {};
  for (int k0 = 0; k0 < K; k0 += 16){
    #pragma unroll
    for (int q = 0; q < 4; q++){
      int e = tid + q*256; int r = e >> 4, kk = e & 15;
      int mi = m0 + r, ki = k0 + kk;
      As[kk][r] = (mi < M && ki < K) ? A[(long)mi*lda + ki] : 0.f;
    }
    #pragma unroll
    for (int q = 0; q < 4; q++){
      int e = tid + q*256; int n = e >> 4, kk = e & 15;
      int ni = n0 + n, ki = k0 + kk;
      Ws[kk][n] = (ni < N && ki < K) ? W[(long)ni*K + ki] : 0.f;
    }
    __syncthreads();
    #pragma unroll
    for (int kk = 0; kk < 16; kk++){
      float4 a4 = *(const float4*)&As[kk][ty*4];
      float4 b4 = *(const float4*)&Ws[kk][tx*4];
      float av[4] = {a4.x, a4.y, a4.z, a4.w};
      float bv[4] = {b4.x, b4.y, b4.z, b4.w};
      #pragma unroll
      for (int mm = 0; mm < 4; mm++)
        #pragma unroll
        for (int nn = 0; nn < 4; nn++) acc[mm][nn] += av[mm]*bv[nn];
    }
    __syncthreads();
  }
  #pragma unroll
  for (int mm = 0; mm < 4; mm++){
    int mi = m0 + ty*4 + mm;
    if (mi >= M) continue;
    #pragma unroll
    for (int nn = 0; nn < 4; nn++){
      int ni = n0 + tx*4 + nn;
      if (ni >= N) continue;
      float v = acc[mm][nn];
      if (bias) v += bias[ni];
      if (act >= 2) v = softplusf(v);
      if (act == 3){
        bf16* Cb = (bf16*)Cbase + (long)z*sC;
        Cb[(long)mi*ldc + ni] = f2b(v);
      } else {
        float* Cp = Cbase + (long)z*sC;
        Cp[(long)mi*ldc + ni] = v;
      }
    }
  }
}

// ---------------- depthwise causal conv1d (k=4) + silu, 8-l rolling window ---------
// grid (16, B, 4), block 512. Each thread: 11-value register window -> 8 outputs.
// Add order per output identical to per-l version (k ascending) -> bit-exact.
__global__ __launch_bounds__(512) void conv1d_kernel(const bf16* __restrict__ xzb,
    const float* __restrict__ fw, const float* __restrict__ fb,
    const float* __restrict__ bw, const float* __restrict__ bb,
    bf16* __restrict__ ub)
{
  int l0 = blockIdx.x*8, b = blockIdx.y, v = blockIdx.z, d = threadIdx.x;
  const bf16* xm = xzb + (long)v*1024*1024;
  const float* w  = (v < 2) ? fw : bw;
  const float* cb = (v < 2) ? fb : bb;
  float w0 = w[d*4], w1 = w[d*4+1], w2 = w[d*4+2], w3 = w[d*4+3];
  float bias = cb[d];
  float r[11];
  #pragma unroll
  for (int i = 0; i < 11; i++){
    int ll = l0 - 3 + i;
    r[i] = (ll >= 0) ? b2f(xm[(long)(b*L_ + ll)*1024 + d]) : 0.f;
  }
  bf16* up = ub + (long)v*1024*512;
  #pragma unroll
  for (int t = 0; t < 8; t++){
    float acc = bias;
    acc += r[t]*w0;
    acc += r[t+1]*w1;
    acc += r[t+2]*w2;
    acc += r[t+3]*w3;
    up[(long)(b*L_ + l0 + t)*512 + d] = f2b(siluf(acc));
  }
}

// ---------------- selective scan (8-way state split, XCD-local block swizzle) ------
// flat grid 2048. fid = g + k*256, g = m + 8*(b + 8*v): the 8 blocks sharing HBM
// cachelines (same (b,v), adjacent d-slices) have ids congruent mod 8 -> same XCD.
// Staging: R9 scalar form (measured better than vectorized-global variant).
// block 64.
__global__ __launch_bounds__(64) void scan_kernel(const bf16* __restrict__ dtb, const bf16* __restrict__ ub,
    const float* __restrict__ dblb, const bf16* __restrict__ xzb,
    const float* __restrict__ fAlog, const float* __restrict__ fD,
    const float* __restrict__ bAlog, const float* __restrict__ bD,
    bf16* __restrict__ yb)
{
  int fid = blockIdx.x;
  int kk2 = fid >> 8;          // 0..7  (within line-sharing group)
  int g   = fid & 255;
  int m   = g & 7;             // d-slice group
  int bv  = g >> 3;            // 0..31
  int b   = bv & 7;
  int v   = bv >> 3;           // 0..3
  int d0  = (m*8 + kk2)*8;
  int tid = threadIdx.x;
  int dd = tid & 7, qtr = tid >> 3;       // qtr in 0..7, 2 states each
  int d = d0 + dd;
  const bf16*  dt  = dtb  + (long)v*1024*512;
  const bf16*  u   = ub   + (long)v*1024*512;
  const float* dbl = dblb + (long)v*1024*48;
  const bf16*  zg  = xzb  + (long)v*1024*1024 + 512;
  const float* Alog = (v < 2) ? fAlog : bAlog;
  const float* Dp   = (v < 2) ? fD : bD;
  __shared__ __align__(16) short sdt[8][136];
  __shared__ __align__(16) short su_[8][136];
  __shared__ __align__(16) short szg[8][136];
  __shared__ __align__(16) short sB [16][136];
  __shared__ __align__(16) short sC [16][136];
  long row = (long)b*L_;
  for (int idx = tid; idx < 1024; idx += 64){
    int l = idx >> 3, j = idx & 7;
    sdt[j][l] = b2s(dt[(row + l)*512 + d0 + j]);
    su_[j][l] = b2s(u[(row + l)*512 + d0 + j]);
    szg[j][l] = b2s(zg[(row + l)*1024 + d0 + j]);
  }
  for (int idx = tid; idx < 2048; idx += 64){
    int l = idx >> 4, j = idx & 15;
    sB[j][l] = b2s(f2b(dbl[(row + l)*48 + 16 + j]));
    sC[j][l] = b2s(f2b(dbl[(row + l)*48 + 32 + j]));
  }
  float a2[2];
  #pragma unroll
  for (int n = 0; n < 2; n++) a2[n] = -expf(Alog[d*16 + qtr*2 + n]) * 1.44269504f;
  float Dv = Dp[d];
  float h[2];
  h[0] = 0.f; h[1] = 0.f;
  __syncthreads();
  bf16* yo = yb + (long)v*1024*512;
  for (int l0 = 0; l0 < 128; l0 += 8){
    bf16x8v dt8 = *(const bf16x8v*)&sdt[dd][l0];
    bf16x8v u8  = *(const bf16x8v*)&su_[dd][l0];
    bf16x8v zg8 = *(const bf16x8v*)&szg[dd][l0];
    bf16x8v B8[2], C8[2];
    #pragma unroll
    for (int n = 0; n < 2; n++){
      B8[n] = *(const bf16x8v*)&sB[qtr*2 + n][l0];
      C8[n] = *(const bf16x8v*)&sC[qtr*2 + n][l0];
    }
    #pragma unroll
    for (int k = 0; k < 8; k++){
      bf16 t0; *(short*)&t0 = dt8[k]; float dtv = b2f(t0);
      bf16 t1; *(short*)&t1 = u8[k];  float uv  = b2f(t1);
      bf16 t2; *(short*)&t2 = zg8[k]; float zgv = b2f(t2);
      float dtu = dtv*uv;
      float acc = 0.f;
      #pragma unroll
      for (int n = 0; n < 2; n++){
        float dA = exp2f(dtv*a2[n]);
        bf16 tb; *(short*)&tb = B8[n][k];
        bf16 tc; *(short*)&tc = C8[n][k];
        h[n] = dA*h[n] + dtu*b2f(tb);
        acc += h[n]*b2f(tc);
      }
      acc += __shfl_xor(acc, 8);
      acc += __shfl_xor(acc, 16);
      acc += __shfl_xor(acc, 32);
      if (qtr == 0)
        yo[(row + l0 + k)*512 + d] = f2b((acc + Dv*uv) * siluf(zgv));
    }
  }
}

// ---------------- LayerNorm over C: mode 1 -> bf16 concat; mode 0 -> fp32 copy -----
// grid (128, B, NV), block 256
__global__ __launch_bounds__(256) void ln_kernel(const float* __restrict__ inb, bf16* __restrict__ outb0,
    bf16* __restrict__ outb1, float* __restrict__ outf,
    const float* __restrict__ lnw, const float* __restrict__ lnb, int mode)
{
  int r = blockIdx.x, b = blockIdx.y, v = blockIdx.z, c = threadIdx.x;
  long row = (long)b*L_ + r;
  float val = inb[((long)v*1024 + row)*C_ + c];
  __shared__ float red[16];
  float s = val, s2 = val*val;
  bred2(s, s2, red);
  float m = s*(1.f/256.f), var = s2*(1.f/256.f) - m*m;
  float o = (val - m)*rsqrtf(vclamp(var))*lnw[c] + lnb[c];
  if (mode == 1){
    long frow = (long)b*L_ + (127 - r);
    if (v == 0)      outb0[row*512 + c] = f2b(o);
    else if (v == 1) outb1[row*512 + c] = f2b(o);
    else if (v == 2) outb0[frow*512 + 256 + c] = f2b(o);
    else             outb1[frow*512 + 256 + c] = f2b(o);
  } else {
    outf[((long)v*1024 + row)*C_ + c] = o;
  }
}

// ---------------- hsig(rm+rn)*clip(bn2(z2)) + gn stats; resq IN-PLACE in z2 --------
// Vectorized bf16x8 reads; packed uint2 writes; 2-register preload; one barrier.
// grid (C, B), block 256
__global__ __launch_bounds__(256) void hsig_kernel(bf16* __restrict__ z2, const float* __restrict__ rm,
    const float* __restrict__ rn, const float* __restrict__ bn2part,
    const float* __restrict__ g2, const float* __restrict__ b2,
    float* __restrict__ gnsum, float* __restrict__ gnsq)
{
  int c = blockIdx.x, b = blockIdx.y, tid = threadIdx.x;
  __shared__ float red[16];
  __shared__ float rms[128], rns[128];
  if (tid < 128){
    rms[tid] = rm[(long)(b*L_ + tid)*C_ + c];
    rns[tid] = rn[(long)(b*L_ + tid)*C_ + c];
  }
  float pa = 0.f, pb = 0.f;
  if (tid < 64){ pa = bn2part[tid*256 + c]; pb = bn2part[16384 + tid*256 + c]; }
  bred2(pa, pb, red);          // internal barriers also cover the rms/rns writes
  float mm2 = pa*(1.f/131072.f);
  float vv2 = pb*(1.f/131072.f) - mm2*mm2;
  float aa = g2[c] * rsqrtf(vclamp(vv2));
  float dd = b2[c] - mm2*aa;
  bf16* zp = z2 + ((long)(b*C_ + c))*16384;
  int j0 = (tid & 15)*8;
  int irow = tid >> 4;
  // preload collision-prone g=0,1 (p < 4096)
  bf16x8v pre0 = *(const bf16x8v*)&zp[0*2048 + tid*8];
  bf16x8v pre1 = *(const bf16x8v*)&zp[1*2048 + tid*8];
  __syncthreads();             // all preloads done before any packed write
  float s = 0.f, s2 = 0.f;
  #pragma unroll
  for (int g = 0; g < 8; g++){
    bf16x8v v8;
    if (g == 0) v8 = pre0;
    else if (g == 1) v8 = pre1;
    else v8 = *(const bf16x8v*)&zp[g*2048 + tid*8];
    int i = g*16 + irow;
    bf16 ov[4];
    #pragma unroll
    for (int k = 0; k < 8; k++){
      bf16 t; *(short*)&t = v8[k];
      float zv = b2f(t)*aa + dd;
      zv = fminf(fmaxf(zv, 0.f), 6.f);
      float gate = rms[i] + rns[j0 + k];
      gate = fminf(fmaxf(gate + 3.f, 0.f), 6.f) * (1.f/6.f);
      float t2 = gate*zv;
      s += t2; s2 += t2*t2;
      if ((k & 1) == 0) ov[k >> 1] = f2b(t2);
    }
    if ((i & 1) == 0)
      *(uint2*)&zp[(i >> 1)*64 + (tid & 15)*4] = *(const uint2*)ov;
  }
  bred2(s, s2, red);
  if (tid == 0){ atomicAdd(&gnsum[b*32 + (c >> 3)], s); atomicAdd(&gnsq[b*32 + (c >> 3)], s2); }
}

// ---------------- FUSED down-pw (swapped-MFMA epilogue, 32KB LDS) ------------------
// grid (64, B), block 256.
__global__ __launch_bounds__(256) void pwdown_fused_kernel(const bf16* __restrict__ z2,
    const float* __restrict__ gnsum, const float* __restrict__ gnsq,
    const float* __restrict__ gn_g, const float* __restrict__ gn_b,
    const bf16* __restrict__ Wb, const float* __restrict__ x,
    float* __restrict__ out, float* __restrict__ sds)
{
  int b = blockIdx.y;
  int p0 = blockIdx.x*64;
  int tid = threadIdx.x;
  __shared__ __align__(16) short Tb[16384];
  __shared__ float gA[256], gD[256];
  {
    float m = gnsum[b*32 + (tid >> 3)]*(1.f/131072.f);
    float v = gnsq[b*32 + (tid >> 3)]*(1.f/131072.f) - m*m;
    float A = rsqrtf(vclamp(v))*gn_g[tid];
    gA[tid] = A; gD[tid] = gn_b[tid] - m*A;
  }
  __syncthreads();
  {
    int pc = tid & 15, ch = tid >> 4;
    #pragma unroll
    for (int it = 0; it < 8; it++){
      int c = (ch + it*16)*2;
      const bf16* r0 = &z2[((long)(b*C_ + c))*16384 + p0 + pc*4];
      bf16x4v va = *(const bf16x4v*)r0;
      bf16x4v vb = *(const bf16x4v*)(r0 + 16384);
      float a0 = gA[c], d0 = gD[c];
      float a1 = gA[c + 1], d1 = gD[c + 1];
      #pragma unroll
      for (int k = 0; k < 4; k++){
        int p = pc*4 + k;
        bf16 h0; *(short*)&h0 = va[k];
        bf16 h1; *(short*)&h1 = vb[k];
        bf16 o0 = f2b(b2f(h0)*a0 + d0);
        bf16 o1 = f2b(b2f(h1)*a1 + d1);
        unsigned int u = ((unsigned int)(*(unsigned short*)&o1) << 16) | (unsigned int)(*(unsigned short*)&o0);
        *(unsigned int*)((char*)Tb + tswz(p, c)) = u;
      }
    }
  }
  __syncthreads();
  int wave = tid >> 6, lane = tid & 63;
  int quad = lane >> 4, l16 = lane & 15;
  f32x4v acc[4][4];
  #pragma unroll
  for (int i = 0; i < 4; i++)
    #pragma unroll
    for (int j = 0; j < 4; j++) acc[i][j] = (f32x4v){0.f, 0.f, 0.f, 0.f};
  for (int k0 = 0; k0 < 256; k0 += 32){
    int c = k0 + quad*8;
    bf16x8v a[4], bb[4];
    #pragma unroll
    for (int ms = 0; ms < 4; ms++)
      a[ms] = *(const bf16x8v*)&Wb[(wave*64 + ms*16 + l16)*C_ + c];
    #pragma unroll
    for (int ns = 0; ns < 4; ns++){
      int p = ns*16 + l16;
      bb[ns] = *(const bf16x8v*)((const char*)Tb + tswz(p, c));
    }
    #pragma unroll
    for (int ms = 0; ms < 4; ms++)
      #pragma unroll
      for (int ns = 0; ns < 4; ns++)
        acc[ms][ns] = __builtin_amdgcn_mfma_f32_16x16x32_bf16(bb[ns], a[ms], acc[ms][ns], 0, 0, 0);
  }
  #pragma unroll
  for (int ms = 0; ms < 4; ms++){
    int o = wave*64 + ms*16 + l16;
    long rowbase = ((long)(b*C_ + o))*4096 + p0;
    float sd = 0.f, sd2 = 0.f, sdx = 0.f;
    #pragma unroll
    for (int ns = 0; ns < 4; ns++){
      f32x4v v4 = acc[ms][ns];
      long base = rowbase + ns*16 + quad*4;
      *(f32x4v*)&out[base] = v4;
      float4 xv = *(const float4*)&x[base];
      sd += v4[0] + v4[1] + v4[2] + v4[3];
      sd2 += v4[0]*v4[0] + v4[1]*v4[1] + v4[2]*v4[2] + v4[3]*v4[3];
      sdx += v4[0]*xv.x + v4[1]*xv.y + v4[2]*xv.z + v4[3]*xv.w;
    }
    sd += __shfl_xor(sd, 16);  sd += __shfl_xor(sd, 32);
    sd2 += __shfl_xor(sd2, 16); sd2 += __shfl_xor(sd2, 32);
    sdx += __shfl_xor(sdx, 16); sdx += __shfl_xor(sdx, 32);
    if (quad == 0){
      int oc = (b << 8) + o;
      atomicAdd(&sds[oc], sd);
      atomicAdd(&sds[2048 + oc], sd2);
      atomicAdd(&sds[4096 + oc], sdx);
    }
  }
}

// ---------------- final: inline coeff + elementwise (float4, G13) ------------------
// out = P*out + Q*x + R, in-place on d_out. grid (C, B), block 256
__global__ __launch_bounds__(256) void final_kernel(const float* __restrict__ x,
    const float* __restrict__ sds, const float* __restrict__ sxb,
    const float* __restrict__ dbn_g, const float* __restrict__ dbn_b,
    const float* __restrict__ gn_g, const float* __restrict__ gn_b,
    float* __restrict__ out)
{
  int c = blockIdx.x, b = blockIdx.y, tid = threadIdx.x;
  __shared__ float lv[11][8];
  int g8 = (c >> 3) << 3;
  if (tid < 8){
    int cc = g8 + tid;
    float sd = 0.f, sd2 = 0.f;
    for (int bb2 = 0; bb2 < 8; bb2++){ sd += sds[bb2*256 + cc]; sd2 += sds[2048 + bb2*256 + cc]; }
    float mB = sd*(1.f/32768.f);
    float vB = sd2*(1.f/32768.f) - mB*mB;
    float ab = dbn_g[cc] * rsqrtf(vclamp(vB));
    float db = dbn_b[cc] - mB*ab;
    float inv_n = 1.f/4096.f;
    float m = sds[b*256 + cc]*inv_n, Ed2 = sds[2048 + b*256 + cc]*inv_n;
    float mx = sxb[b*256 + cc]*inv_n, Ex2 = sxb[2048 + b*256 + cc]*inv_n;
    float Edx = sds[4096 + b*256 + cc]*inv_n;
    float Ev = ab*m + db;
    float Ev2 = ab*ab*Ed2 + 2.f*ab*db*m + db*db;
    lv[0][tid] = ab; lv[1][tid] = db; lv[2][tid] = m; lv[3][tid] = Ed2;
    lv[4][tid] = mx; lv[5][tid] = Ex2; lv[6][tid] = Edx; lv[7][tid] = Ev; lv[8][tid] = Ev2;
  }
  __syncthreads();
  if (tid < 8){
    float m1 = 0.f, q1 = 0.f;
    for (int k = 0; k < 8; k++){ m1 += lv[7][k]; q1 += lv[8][k]; }
    m1 *= 0.125f; q1 *= 0.125f;
    int cc = g8 + tid;
    float inv1 = rsqrtf(vclamp(q1 - m1*m1));
    float A1 = inv1*gn_g[cc];
    float D1 = gn_b[cc] - m1*A1;
    float ab = lv[0][tid], db = lv[1][tid];
    float m = lv[2][tid], Ed2 = lv[3][tid], mx = lv[4][tid], Ex2 = lv[5][tid], Edx = lv[6][tid];
    float al = A1*ab;
    float be = A1*db + D1;
    float Et = al*m + be + mx;
    float Et2 = al*al*Ed2 + 2.f*al*be*m + be*be + 2.f*al*Edx + 2.f*be*mx + Ex2;
    lv[9][tid] = Et; lv[10][tid] = Et2; lv[0][tid] = al; lv[1][tid] = be;
  }
  __syncthreads();
  float m2 = 0.f, q2 = 0.f;
  for (int k = 0; k < 8; k++){ m2 += lv[9][k]; q2 += lv[10][k]; }
  m2 *= 0.125f; q2 *= 0.125f;
  float G = rsqrtf(vclamp(q2 - m2*m2))*gn_g[c];
  float P = G*lv[0][c & 7];
  float Q = G;
  float R = G*(lv[1][c & 7] - m2) + gn_b[c];
  long base = ((long)(b*C_ + c))*1024;      // float4 units
  const float4* x4 = (const float4*)x;
  float4* o4 = (float4*)out;
  #pragma unroll
  for (int it = 0; it < 4; it++){
    long idx = base + it*256 + tid;
    float4 o = o4[idx];
    float4 xv = x4[idx];
    o.x = P*o.x + Q*xv.x + R;
    o.y = P*o.y + Q*xv.y + R;
    o.z = P*o.z + Q*xv.z + R;
    o.w = P*o.w + Q*xv.w + R;
    o4[idx] = o;
  }
}

extern "C" void kernel_launch(void* const* d_in, const int* in_sizes, int n_in,
                              void* d_out, int out_size, void* d_ws, size_t ws_size,
                              hipStream_t stream)
{
  (void)in_sizes; (void)n_in; (void)out_size; (void)ws_size;
  // ALL inputs/outputs are float32.
  const float* x         = (const float*)d_in[0];
  const float* pos       = (const float*)d_in[1];
  const float* ln_w      = (const float*)d_in[2];
  const float* ln_b      = (const float*)d_in[3];
  const float* proj_w    = (const float*)d_in[4];
  const float* proj_b    = (const float*)d_in[5];
  const float* up_dw_w   = (const float*)d_in[6];
  const float* up_bn1_g  = (const float*)d_in[7];
  const float* up_bn1_b  = (const float*)d_in[8];
  const float* up_pw_w   = (const float*)d_in[9];
  const float* up_bn2_g  = (const float*)d_in[10];
  const float* up_bn2_b  = (const float*)d_in[11];
  const float* down_pw_w = (const float*)d_in[12];
  const float* down_bn_g = (const float*)d_in[13];
  const float* down_bn_b = (const float*)d_in[14];
  const float* gn_g      = (const float*)d_in[15];
  const float* gn_b      = (const float*)d_in[16];
  const float* f_in_w    = (const float*)d_in[17];
  const float* f_conv_w  = (const float*)d_in[18];
  const float* f_conv_b  = (const float*)d_in[19];
  const float* f_xproj_w = (const float*)d_in[20];
  const float* f_dt_w    = (const float*)d_in[21];
  const float* f_dt_b    = (const float*)d_in[22];
  const float* f_Alog    = (const float*)d_in[23];
  const float* f_D       = (const float*)d_in[24];
  const float* f_out_w   = (const float*)d_in[25];
  const float* b_in_w    = (const float*)d_in[26];
  const float* b_conv_w  = (const float*)d_in[27];
  const float* b_conv_b  = (const float*)d_in[28];
  const float* b_xproj_w = (const float*)d_in[29];
  const float* b_dt_w    = (const float*)d_in[30];
  const float* b_dt_b    = (const float*)d_in[31];
  const float* b_Alog    = (const float*)d_in[32];
  const float* b_D       = (const float*)d_in[33];
  const float* b_out_w   = (const float*)d_in[34];

  // ======== workspace layout ========
  char* sb = (char*)d_ws;
  float* statz  = (float*)(sb);               // 1536 f [zeroed]: bn1(512) unused(512) gn(512)
  float* sds    = (float*)(sb + 6144);        // 6144 f [zeroed]: sd | sd2 | sdx (b*256+c)
  float* bn2part= (float*)(sb + 32768);       // 32768 f [zeroed]: [64][256] sum | sq
  float* sxb    = (float*)(sb + 184320);      // 4096 f: sum x | sum x^2 (b*256+c)
  float* rmrn  = (float*)(sb + 1*MB);        // 2MB: 2 x (1024,256)
  bf16*  Wbbuf = (bf16*)(sb + 3*MB);         // 128KB: up_pw_w bf16
  bf16*  Wb2buf= (bf16*)(sb + 3*MB + 262144);// 128KB: down_pw_w bf16
  bf16*  Wpb   = (bf16*)(sb + 3*MB + 524288);// 256KB: proj_w bf16
  char* big = sb + 4*MB;
  float* pool4  = (float*)(big + 0*MB);      // 2 MB
  bf16*  hbufb  = (bf16*)(big + 2*MB);       // 2 MB: 4 x (B*L,C) bf16
  bf16*  Wif    = (bf16*)(big + 4*MB);       // 512KB: f_in_w bf16
  bf16*  Wib2   = (bf16*)(big + 4*MB + 524288); // 512KB: b_in_w bf16
  bf16*  Wxf    = (bf16*)(big + 5*MB);           // 48KB: f_xproj_w bf16
  bf16*  Wxb    = (bf16*)(big + 5*MB + 65536);   // 48KB: b_xproj_w bf16
  bf16*  Wof    = (bf16*)(big + 5*MB + 131072);  // 256KB: f_out_w bf16
  bf16*  Wob    = (bf16*)(big + 5*MB + 393216);  // 256KB: b_out_w bf16
  bf16*  xzbuf  = (bf16*)(big + 6*MB);       // 8 MB: 4 x (1024,1024) bf16
  bf16*  ubuf   = (bf16*)(big + 22*MB);      // 4 MB: 4 x (1024,512) bf16
  float* dblbuf = (float*)(big + 30*MB);     // 768 KB
  bf16*  dtbuf  = (bf16*)(big + 31*MB);      // 4 MB: 4 x (1024,512) bf16
  bf16*  ybuf   = (bf16*)(big + 39*MB);      // 4 MB: 4 x (1024,512) bf16
  float* mout   = (float*)(big + 47*MB);     // 4 MB
  bf16*  cbufb  = (bf16*)(big + 51*MB);      // 2 MB: 2 x (1024,512) bf16
  float* respre = (float*)(big + 55*MB);     // 2 MB  (ends at 57MB < 64MB)
  bf16*  z1buf  = (bf16*)(big);              // 64 MiB bf16, c-major (phase 2)
  bf16*  z2buf  = (bf16*)(big);              // 64 MiB bf16 (in-place over z1)
  float* dbuf   = (float*)d_out;             // 32 MB fp32 (phase 3)

  float* bn1sum = statz;        float* bn1sq = statz + 256;
  float* gnsum  = statz + 1024; float* gnsq  = statz + 1280;
  float* pcolmax = pool4;
  float* pcolmin = pool4 + 131072;
  float* prowmax = pool4 + 262144;
  float* prowmin = pool4 + 393216;

  hipMemsetAsync(statz, 0, 163840, stream);   // statz + sds + bn2part

  // ---- all weight converts in one launch ----
  wcvt_all_kernel<<<dim3(256, 9), 256, 0, stream>>>(
      f_in_w, b_in_w, f_xproj_w, b_xproj_w, f_out_w, b_out_w, proj_w, up_pw_w, down_pw_w,
      Wif, Wib2, Wxf, Wxb, Wof, Wob, Wpb, Wbbuf, Wb2buf);

  // ---- phase 1: pooling + LN + mamba x4 (f/b x max/min) -> rmrn ----
  pool1_kernel<<<dim3(256, 8), 64, 0, stream>>>(x, pos, pcolmax, pcolmin, prowmax, prowmin, sxb);
  pool2_kernel<<<dim3(128, 8), 256, 0, stream>>>(pcolmax, pcolmin, prowmax, prowmin, ln_w, ln_b, hbufb);
  inproj_mfma_kernel<<<dim3(16, 4, 4), 256, 0, stream>>>(hbufb, Wif, Wib2, xzbuf);
  conv1d_kernel<<<dim3(16, 8, 4), 512, 0, stream>>>(xzbuf, f_conv_w, f_conv_b, b_conv_w, b_conv_b, ubuf);
  xproj_mfma_kernel<<<dim3(4, 4), 256, 0, stream>>>(ubuf, Wxf, Wxb, dblbuf);
  gemm_kernel<<<dim3(8, 16, 4), 256, 0, stream>>>(dblbuf, 49152, 48, f_dt_w, b_dt_w, f_dt_b, b_dt_b, 2,
                                                  (float*)dtbuf, 524288, 512, 1024, 512, 16, 3);
  scan_kernel<<<2048, 64, 0, stream>>>(dtbuf, ubuf, dblbuf, xzbuf, f_Alog, f_D, b_Alog, b_D, ybuf);
  outproj_mfma_kernel<<<dim3(4, 4, 4), 256, 0, stream>>>(ybuf, Wof, Wob, mout);
  ln_kernel<<<dim3(128, 8, 4), 256, 0, stream>>>(mout, cbufb, cbufb + 524288, nullptr, ln_w, ln_b, 1);
  pj_mfma_kernel<<<dim3(4, 4, 2), 256, 0, stream>>>(cbufb, Wpb, proj_b, respre);
  ln_kernel<<<dim3(128, 8, 2), 256, 0, stream>>>(respre, nullptr, nullptr, rmrn, ln_w, ln_b, 0);

  // ---- phase 2: z path (dwconvT -> bn1 -> relu -> pw -> bn2 partials, fused) ----
  dwz1_kernel<<<2048, 256, 0, stream>>>(x, up_dw_w, z1buf, bn1sum, bn1sq);
  pwz_fused_kernel<<<dim3(256, 8), 256, 0, stream>>>(z1buf, bn1sum, bn1sq, up_bn1_g, up_bn1_b,
                                                     Wbbuf, z2buf, bn2part);

  // ---- phase 3: merge + tail ----
  hsig_kernel<<<dim3(256, 8), 256, 0, stream>>>(z2buf, rmrn, rmrn + 262144, bn2part,
                                                up_bn2_g, up_bn2_b, gnsum, gnsq);
  pwdown_fused_kernel<<<dim3(64, 8), 256, 0, stream>>>(z2buf, gnsum, gnsq, gn_g, gn_b,
                                                       Wb2buf, x, dbuf, sds);
  final_kernel<<<dim3(256, 8), 256, 0, stream>>>(x, sds, sxb, down_bn_g, down_bn_b, gn_g, gn_b,
                                                 (float*)d_out);
}